// Round 6
// baseline (289.945 us; speedup 1.0000x reference)
//
#include <hip/hip_runtime.h>
#include <math.h>

// Chained bilinear lookup: out = bilinear(grid0, bilinear(grid1, x)),
// sigmoid per corner sample (both stages).
//
// Shapes: x (N,2) f32; grid1 (U1,U1,2) f32, U1=2080; grid0 (U0,U0,3) f32,
// U0=520; out (N,3) f32.
//
// PRECISION CONTRACT (R0-R16, passing at absmax 3.9e-3 / thr 1.96e-2):
//  - Ref is a faithful per-op float32 numpy pipeline; stage-1 output is
//    multiplied by 520 in stage 2 (errors amplified ~520x).
//  - su = x*U must be a SINGLE f32 rounded mul (inline-asm v_mul_f32 —
//    default ffp-contract otherwise fuses su-floor into fma => 0.04).
//  - Sigmoid: e = expf(-t) in f32 (1 ulp, matches np.exp-f32), then
//    1/(1+e) in f64 rounded once to f32. Moving sigmoid between pack
//    and query is value-identical (same fn, same inputs, same order).
//  - f32 blends as written (R5/R8-validated).
//
// PERF HISTORY:
//  R5:  s1-table query (2 rows/pt): 179us @ FETCH 600MB = 3.35TB/s.
//  R8:  32B-cell packed query: 123.7us @ 312MB (min-fetch shape);
//       LDS-tiled pack 137us.
//  R11: total 257.1 = query 124.7 + remainder 132.4.
//  R14: nt LOADS in query: -41% (L1 bypass kills line reuse). REVERT.
//       nt STORES in pack: +16us vs plain. KEEP for any pack.
//  R15: pk L3-warm residency worth ZERO to query (123.7 either way).
//  R16: rowpair pack (69MB wr): query 141us @350MB (8 in-kernel
//       sigmoids nearly free: VALUBusy 15->32%, latency-bound);
//       remainder only -9.4us vs R14 despite -69MB pack bytes =>
//       marginal pack BW ~7.3TB/s but a ~95-105us FLOOR for ANY
//       grid1 pre-pass (3 structures all pay it). Bytes are cheap,
//       the pre-pass itself is not.
//  R17 (this): ELIMINATE the grid1 pre-pass. Query reads raw g1
//       directly (4 float2 corner loads, 2 rows/pt — R5-measured
//       3.35TB/s on identical layout) + 8 in-kernel sigmoids (R16-
//       proven cheap). Keep only tiny s0 pre-pass (6.4MB, ~4us).
//       Predict query 180-200us @ ~640MB, total ~190-210us,
//       absmax unchanged 0.00390625. If total-query >> 15us, a fixed
//       harness cost exists -> next-round redirect.

typedef float f32x2 __attribute__((ext_vector_type(2)));
typedef float f32x4 __attribute__((ext_vector_type(4)));

__device__ __forceinline__ float mul_rn_nocontract(float a, float b) {
    float r;
    asm("v_mul_f32 %0, %1, %2" : "=v"(r) : "v"(a), "v"(b));
    return r;
}

// ~1-ulp sigmoid matching numpy's f32 chain: e rounded to f32 (like
// np.exp on float32), then a single correctly-rounded divide (f64 math
// is immune to any rcp/fast lowering of f32 division).
__device__ __forceinline__ float sigmoid_ref(float t) {
    float e = expf(-t);                      // ocml expf, ~1 ulp f32
    return (float)(1.0 / (1.0 + (double)e)); // exact add+div, one rounding
}

// ---- Phase A: elementwise sigmoid of a table (float4-vectorized) ----
__global__ void __launch_bounds__(256) sigmoid_table_kernel(
    const float4* __restrict__ in, float4* __restrict__ out, int n4)
{
    int i = blockIdx.x * blockDim.x + threadIdx.x;
    if (i >= n4) return;
    float4 v = in[i];
    float4 r;
    r.x = sigmoid_ref(v.x);
    r.y = sigmoid_ref(v.y);
    r.z = sigmoid_ref(v.z);
    r.w = sigmoid_ref(v.w);
    out[i] = r;
}

// ---- Phase B: direct query (no grid1 pre-pass) ----
// 1 pt/thread: 4 raw float2 corner loads from g1 (rows u0,u0+1; cols
// v0,v0+1 adjacent -> ~2.25 lines/pt, R5-measured 3.35TB/s), 8 stage-1
// sigmoids in-kernel (R16: hidden under memory latency), stage 2 via
// pre-sigmoided s0 (3.2MB, cache-resident).
__global__ void __launch_bounds__(256) query_direct_kernel(
    const float* __restrict__ x,
    const float* __restrict__ g1,   // raw grid1, (U1,U1,2)
    const float* __restrict__ s0,   // sigmoid(grid0), (U0,U0,3)
    float* __restrict__ out,        // (N,3)
    int N, int U1, int U0)
{
    int i = blockIdx.x * blockDim.x + threadIdx.x;
    if (i >= N) return;

    f32x2 uv = __builtin_nontemporal_load(
        reinterpret_cast<const f32x2*>(x) + i);

    // stage-1 coords: single rounded f32 mul (contract-proof)
    float fU1 = (float)U1;
    float su = mul_rn_nocontract(uv.x, fU1);
    float sv = mul_rn_nocontract(uv.y, fU1);
    float u0f = floorf(su), v0f = floorf(sv);
    float fu = su - u0f;              // exact
    float fv = sv - v0f;
    int u0 = (int)u0f % U1; if (u0 < 0) u0 += U1;
    int v0 = (int)v0f % U1; if (v0 < 0) v0 += U1;
    int u1 = u0 + 1; if (u1 >= U1) u1 = 0;
    int v1 = v0 + 1; if (v1 >= U1) v1 = 0;

    // PLAIN loads (R14: nt loads cost +41% here — need L1/L2 reuse)
    const f32x2* g = reinterpret_cast<const f32x2*>(g1);
    const f32x2* row0 = g + (size_t)u0 * U1;
    const f32x2* row1 = g + (size_t)u1 * U1;
    f32x2 t00 = row0[v0];
    f32x2 t01 = row0[v1];
    f32x2 t10 = row1[v0];
    f32x2 t11 = row1[v1];

    // stage-1 sigmoids in-kernel (identical fn/order as packed paths)
    float a00x = sigmoid_ref(t00.x), a00y = sigmoid_ref(t00.y);
    float a10x = sigmoid_ref(t10.x), a10y = sigmoid_ref(t10.y);
    float a01x = sigmoid_ref(t01.x), a01y = sigmoid_ref(t01.y);
    float a11x = sigmoid_ref(t11.x), a11y = sigmoid_ref(t11.y);

    float omfu = 1.0f - fu, omfv = 1.0f - fv;
    float kx = (a00x * omfu + a10x * fu) * omfv
             + (a01x * omfu + a11x * fu) * fv;
    float ky = (a00y * omfu + a10y * fu) * omfv
             + (a01y * omfu + a11y * fu) * fv;

    // stage 2 (R5/R8-validated form, cache-resident 3.2MB AoS table)
    float fU0 = (float)U0;
    float su2 = mul_rn_nocontract(kx, fU0);
    float sv2 = mul_rn_nocontract(ky, fU0);
    float u0f2 = floorf(su2), v0f2 = floorf(sv2);
    float fu2 = su2 - u0f2, fv2 = sv2 - v0f2;
    int p0 = (int)u0f2 % U0; if (p0 < 0) p0 += U0;
    int q0 = (int)v0f2 % U0; if (q0 < 0) q0 += U0;
    int p1 = p0 + 1; if (p1 >= U0) p1 = 0;
    int q1 = q0 + 1; if (q1 >= U0) q1 = 0;
    int b00 = (p0 * U0 + q0) * 3, b10 = (p1 * U0 + q0) * 3;
    int b01 = (p0 * U0 + q1) * 3, b11 = (p1 * U0 + q1) * 3;
    float omfu2 = 1.0f - fu2, omfv2 = 1.0f - fv2;
    float r0 = (s0[b00+0] * omfu2 + s0[b10+0] * fu2) * omfv2
             + (s0[b01+0] * omfu2 + s0[b11+0] * fu2) * fv2;
    float r1 = (s0[b00+1] * omfu2 + s0[b10+1] * fu2) * omfv2
             + (s0[b01+1] * omfu2 + s0[b11+1] * fu2) * fv2;
    float r2 = (s0[b00+2] * omfu2 + s0[b10+2] * fu2) * omfv2
             + (s0[b01+2] * omfu2 + s0[b11+2] * fu2) * fv2;
    out[3*i+0] = r0; out[3*i+1] = r1; out[3*i+2] = r2;
}

// ---- Full fallback: all sigmoids in-kernel (ws too small for s0) ----
__global__ void __launch_bounds__(256) query_kernel_fallback(
    const float* __restrict__ x,
    const float* __restrict__ g1,
    const float* __restrict__ g0,
    float* __restrict__ out,
    int N, int U1, int U0)
{
    int i = blockIdx.x * blockDim.x + threadIdx.x;
    if (i >= N) return;
    float2 uv = reinterpret_cast<const float2*>(x)[i];
    float fU1 = (float)U1;
    float su = mul_rn_nocontract(uv.x, fU1);
    float sv = mul_rn_nocontract(uv.y, fU1);
    float u0f = floorf(su), v0f = floorf(sv);
    float fu = su - u0f, fv = sv - v0f;
    int u0 = (int)u0f % U1; if (u0 < 0) u0 += U1;
    int v0 = (int)v0f % U1; if (v0 < 0) v0 += U1;
    int u1 = u0 + 1; if (u1 >= U1) u1 = 0;
    int v1 = v0 + 1; if (v1 >= U1) v1 = 0;
    const float2* g1v = reinterpret_cast<const float2*>(g1);
    float2 t00 = g1v[u0 * U1 + v0];
    float2 t10 = g1v[u1 * U1 + v0];
    float2 t01 = g1v[u0 * U1 + v1];
    float2 t11 = g1v[u1 * U1 + v1];
    float a00x = sigmoid_ref(t00.x), a00y = sigmoid_ref(t00.y);
    float a10x = sigmoid_ref(t10.x), a10y = sigmoid_ref(t10.y);
    float a01x = sigmoid_ref(t01.x), a01y = sigmoid_ref(t01.y);
    float a11x = sigmoid_ref(t11.x), a11y = sigmoid_ref(t11.y);
    float omfu = 1.0f - fu, omfv = 1.0f - fv;
    float kx = (a00x * omfu + a10x * fu) * omfv + (a01x * omfu + a11x * fu) * fv;
    float ky = (a00y * omfu + a10y * fu) * omfv + (a01y * omfu + a11y * fu) * fv;
    float fU0 = (float)U0;
    float su2 = mul_rn_nocontract(kx, fU0);
    float sv2 = mul_rn_nocontract(ky, fU0);
    float u0f2 = floorf(su2), v0f2 = floorf(sv2);
    float fu2 = su2 - u0f2, fv2 = sv2 - v0f2;
    int p0 = (int)u0f2 % U0; if (p0 < 0) p0 += U0;
    int q0 = (int)v0f2 % U0; if (q0 < 0) q0 += U0;
    int p1 = p0 + 1; if (p1 >= U0) p1 = 0;
    int q1 = q0 + 1; if (q1 >= U0) q1 = 0;
    int b00 = (p0 * U0 + q0) * 3, b10 = (p1 * U0 + q0) * 3;
    int b01 = (p0 * U0 + q1) * 3, b11 = (p1 * U0 + q1) * 3;
    float omfu2 = 1.0f - fu2, omfv2 = 1.0f - fv2;
    float r0 = (sigmoid_ref(g0[b00+0]) * omfu2 + sigmoid_ref(g0[b10+0]) * fu2) * omfv2
             + (sigmoid_ref(g0[b01+0]) * omfu2 + sigmoid_ref(g0[b11+0]) * fu2) * fv2;
    float r1 = (sigmoid_ref(g0[b00+1]) * omfu2 + sigmoid_ref(g0[b10+1]) * fu2) * omfv2
             + (sigmoid_ref(g0[b01+1]) * omfu2 + sigmoid_ref(g0[b11+1]) * fu2) * fv2;
    float r2 = (sigmoid_ref(g0[b00+2]) * omfu2 + sigmoid_ref(g0[b10+2]) * fu2) * omfv2
             + (sigmoid_ref(g0[b01+2]) * omfu2 + sigmoid_ref(g0[b11+2]) * fu2) * fv2;
    out[3*i+0] = r0; out[3*i+1] = r1; out[3*i+2] = r2;
}

extern "C" void kernel_launch(void* const* d_in, const int* in_sizes, int n_in,
                              void* d_out, int out_size, void* d_ws, size_t ws_size,
                              hipStream_t stream) {
    const float* x  = (const float*)d_in[0];
    const float* g1 = (const float*)d_in[1];
    const float* g0 = (const float*)d_in[2];
    float* out = (float*)d_out;

    int N = in_sizes[0] / 2;
    long long n1 = in_sizes[1];          // U1*U1*2
    long long n0 = in_sizes[2];          // U0*U0*3
    int U1 = (int)(sqrt((double)(n1 / 2)) + 0.5);
    int U0 = (int)(sqrt((double)(n0 / 3)) + 0.5);
    (void)n1;

    int block = 256;
    size_t need_s0 = (size_t)n0 * sizeof(float);

    if (ws_size >= need_s0 && (n0 % 4) == 0) {
        float* s0 = (float*)d_ws;                     // 3.2 MB sigmoided g0
        int n0_4 = (int)(n0 / 4);
        sigmoid_table_kernel<<<(n0_4 + block - 1) / block, block, 0, stream>>>(
            (const float4*)g0, (float4*)s0, n0_4);
        query_direct_kernel<<<(N + block - 1) / block, block, 0, stream>>>(
            x, g1, s0, out, N, U1, U0);
    } else {
        query_kernel_fallback<<<(N + block - 1) / block, block, 0, stream>>>(
            x, g1, g0, out, N, U1, U0);
    }
}

// Round 7
// 276.271 us; speedup vs baseline: 1.0495x; 1.0495x over previous
//
#include <hip/hip_runtime.h>
#include <math.h>

// Chained bilinear lookup: out = bilinear(grid0, bilinear(grid1, x)),
// sigmoid per corner sample (both stages).
//
// Shapes: x (N,2) f32; grid1 (U1,U1,2) f32, U1=2080; grid0 (U0,U0,3) f32,
// U0=520; out (N,3) f32.
//
// PRECISION CONTRACT (R0-R17, passing at absmax 3.9e-3 / thr 1.96e-2):
//  - Ref is a faithful per-op float32 numpy pipeline; stage-1 output is
//    multiplied by 520 in stage 2 (errors amplified ~520x).
//  - su = x*U must be a SINGLE f32 rounded mul (inline-asm v_mul_f32 —
//    default ffp-contract otherwise fuses su-floor into fma => 0.04).
//  - Sigmoid: e = expf(-t) in f32 (1 ulp, matches np.exp-f32), then
//    1/(1+e) in f64 rounded once to f32. Moving sigmoid between pack
//    and query is value-identical (same fn, same inputs, same order).
//  - f32 blends as written (R5/R8-validated).
//
// COST MODEL (discovered R17): dur_us = kernels + ~88us FIXED harness
// overhead (independent of workspace size / kernel count). Verified to
// ~1us against R11/R14/R15/R16/R17. Measured component costs:
//   query_packed (plain loads): 123.7us @ FETCH 312MB (2.99 TB/s)
//   query_rowpair:              141.3us @ 350MB
//   query_direct (no pack):     197.4us @ 640MB (3.54 TB/s)
//   pack tiled/fused-plain/fused-nt/rowpair-nt: 40/44/28/18us
// => minimize query+pack: fused-nt(28) + query_packed(123.7) + sig(4)
//    = 156us kernels -> ~244us total. (R16 was 163, R17 was 201.)
//
// PERF HISTORY (key A/Bs):
//  R14: nt LOADS in query: -41% (L1 bypass kills line reuse). NEVER.
//       nt STORES in pack: +16us vs plain. ALWAYS for pack.
//  R15: pk L3-warm residency worth ZERO to query. Don't chase it.
//  R16: in-query sigmoids ~free (latency-bound, VALUBusy 15->32%).
//  R17: "pre-pass floor" REFUTED — was the fixed 88us overhead.
//  R18 (this): fused-nt pack + R8 query_packed + s0 sigmoid.
//       Predict total 242-248us, absmax 0.00390625.

typedef float f32x2 __attribute__((ext_vector_type(2)));
typedef float f32x4 __attribute__((ext_vector_type(4)));

__device__ __forceinline__ float mul_rn_nocontract(float a, float b) {
    float r;
    asm("v_mul_f32 %0, %1, %2" : "=v"(r) : "v"(a), "v"(b));
    return r;
}

// ~1-ulp sigmoid matching numpy's f32 chain: e rounded to f32 (like
// np.exp on float32), then a single correctly-rounded divide (f64 math
// is immune to any rcp/fast lowering of f32 division).
__device__ __forceinline__ float sigmoid_ref(float t) {
    float e = expf(-t);                      // ocml expf, ~1 ulp f32
    return (float)(1.0 / (1.0 + (double)e)); // exact add+div, one rounding
}

// ---- Phase A1: fused corner-pack of grid1 (barrier-free, nt stores) ----
// One thread per cell (u,v):
//   pk cell = [s(t00).xy s(t01).xy | s(t10).xy s(t11).xy]  (32B)
// No LDS, no barrier, no int div. Corner sigmoids recomputed 4x (VALU
// hidden under the 138MB write stream). nt stores: +16us vs plain (R14
// vs R15 isolated A/B); pk L3 residency is worthless to query (R15).
__global__ void __launch_bounds__(256) pack_fused_kernel(
    const float* __restrict__ g1, float* __restrict__ pk, int U1)
{
    int v = blockIdx.x * 256 + threadIdx.x;
    int u = blockIdx.y;
    if (v >= U1) return;
    int v1 = v + 1; if (v1 >= U1) v1 = 0;
    int u1 = u + 1; if (u1 >= U1) u1 = 0;

    const f32x2* g = reinterpret_cast<const f32x2*>(g1);
    size_t ru0 = (size_t)u  * U1;
    size_t ru1 = (size_t)u1 * U1;
    f32x2 t00 = g[ru0 + v];
    f32x2 t01 = g[ru0 + v1];
    f32x2 t10 = g[ru1 + v];
    f32x2 t11 = g[ru1 + v1];

    f32x4 lo, hi;
    lo.x = sigmoid_ref(t00.x); lo.y = sigmoid_ref(t00.y);
    lo.z = sigmoid_ref(t01.x); lo.w = sigmoid_ref(t01.y);
    hi.x = sigmoid_ref(t10.x); hi.y = sigmoid_ref(t10.y);
    hi.z = sigmoid_ref(t11.x); hi.w = sigmoid_ref(t11.y);

    f32x4* o = reinterpret_cast<f32x4*>(pk + (ru0 + v) * 8);
    __builtin_nontemporal_store(lo, o);
    __builtin_nontemporal_store(hi, o + 1);
}

// ---- Phase A2: elementwise sigmoid of a table (float4-vectorized) ----
__global__ void __launch_bounds__(256) sigmoid_table_kernel(
    const float4* __restrict__ in, float4* __restrict__ out, int n4)
{
    int i = blockIdx.x * blockDim.x + threadIdx.x;
    if (i >= n4) return;
    float4 v = in[i];
    float4 r;
    r.x = sigmoid_ref(v.x);
    r.y = sigmoid_ref(v.y);
    r.z = sigmoid_ref(v.z);
    r.w = sigmoid_ref(v.w);
    out[i] = r;
}

// ---- Phase B: R8/R11 query (1 pt/thread, packed stage-1, AoS stage-2) ----
// PLAIN cell loads (R14: nt loads cost +41%). 123.7us reproduced 4x.
__global__ void __launch_bounds__(256) query_packed_kernel(
    const float* __restrict__ x,
    const float* __restrict__ pk,   // packed corners, U1*U1*8 floats
    const float* __restrict__ s0,   // sigmoid(grid0), (U0,U0,3), L2-resident
    float* __restrict__ out,        // (N,3)
    int N, int U1, int U0)
{
    int i = blockIdx.x * blockDim.x + threadIdx.x;
    if (i >= N) return;

    f32x2 uv = __builtin_nontemporal_load(
        reinterpret_cast<const f32x2*>(x) + i);

    // stage-1 coords: single rounded f32 mul (contract-proof)
    float fU1 = (float)U1;
    float su = mul_rn_nocontract(uv.x, fU1);
    float sv = mul_rn_nocontract(uv.y, fU1);
    float u0f = floorf(su), v0f = floorf(sv);
    float fu = su - u0f;              // exact
    float fv = sv - v0f;
    int u0 = (int)u0f % U1; if (u0 < 0) u0 += U1;
    int v0 = (int)v0f % U1; if (v0 < 0) v0 += U1;

    // ONE 64B line: 32B-aligned packed cell, plain loads
    const float4* cell = reinterpret_cast<const float4*>(pk)
                       + (size_t)(u0 * U1 + v0) * 2;
    float4 lo = cell[0];   // t00.xy t01.xy
    float4 hi = cell[1];   // t10.xy t11.xy

    float omfu = 1.0f - fu, omfv = 1.0f - fv;
    float kx = (lo.x * omfu + hi.x * fu) * omfv
             + (lo.z * omfu + hi.z * fu) * fv;
    float ky = (lo.y * omfu + hi.y * fu) * omfv
             + (lo.w * omfu + hi.w * fu) * fv;

    // stage 2 (R5/R8-validated form, cache-resident 3.2MB AoS table)
    float fU0 = (float)U0;
    float su2 = mul_rn_nocontract(kx, fU0);
    float sv2 = mul_rn_nocontract(ky, fU0);
    float u0f2 = floorf(su2), v0f2 = floorf(sv2);
    float fu2 = su2 - u0f2, fv2 = sv2 - v0f2;
    int p0 = (int)u0f2 % U0; if (p0 < 0) p0 += U0;
    int q0 = (int)v0f2 % U0; if (q0 < 0) q0 += U0;
    int p1 = p0 + 1; if (p1 >= U0) p1 = 0;
    int q1 = q0 + 1; if (q1 >= U0) q1 = 0;
    int b00 = (p0 * U0 + q0) * 3, b10 = (p1 * U0 + q0) * 3;
    int b01 = (p0 * U0 + q1) * 3, b11 = (p1 * U0 + q1) * 3;
    float omfu2 = 1.0f - fu2, omfv2 = 1.0f - fv2;
    float r0 = (s0[b00+0] * omfu2 + s0[b10+0] * fu2) * omfv2
             + (s0[b01+0] * omfu2 + s0[b11+0] * fu2) * fv2;
    float r1 = (s0[b00+1] * omfu2 + s0[b10+1] * fu2) * omfv2
             + (s0[b01+1] * omfu2 + s0[b11+1] * fu2) * fv2;
    float r2 = (s0[b00+2] * omfu2 + s0[b10+2] * fu2) * omfv2
             + (s0[b01+2] * omfu2 + s0[b11+2] * fu2) * fv2;
    out[3*i+0] = r0; out[3*i+1] = r1; out[3*i+2] = r2;
}

// ---- Middle variant: direct query, no grid1 pre-pass (R17, 197us) ----
__global__ void __launch_bounds__(256) query_direct_kernel(
    const float* __restrict__ x,
    const float* __restrict__ g1,
    const float* __restrict__ s0,
    float* __restrict__ out,
    int N, int U1, int U0)
{
    int i = blockIdx.x * blockDim.x + threadIdx.x;
    if (i >= N) return;

    f32x2 uv = __builtin_nontemporal_load(
        reinterpret_cast<const f32x2*>(x) + i);

    float fU1 = (float)U1;
    float su = mul_rn_nocontract(uv.x, fU1);
    float sv = mul_rn_nocontract(uv.y, fU1);
    float u0f = floorf(su), v0f = floorf(sv);
    float fu = su - u0f, fv = sv - v0f;
    int u0 = (int)u0f % U1; if (u0 < 0) u0 += U1;
    int v0 = (int)v0f % U1; if (v0 < 0) v0 += U1;
    int u1 = u0 + 1; if (u1 >= U1) u1 = 0;
    int v1 = v0 + 1; if (v1 >= U1) v1 = 0;

    const f32x2* g = reinterpret_cast<const f32x2*>(g1);
    const f32x2* row0 = g + (size_t)u0 * U1;
    const f32x2* row1 = g + (size_t)u1 * U1;
    f32x2 t00 = row0[v0];
    f32x2 t01 = row0[v1];
    f32x2 t10 = row1[v0];
    f32x2 t11 = row1[v1];

    float a00x = sigmoid_ref(t00.x), a00y = sigmoid_ref(t00.y);
    float a10x = sigmoid_ref(t10.x), a10y = sigmoid_ref(t10.y);
    float a01x = sigmoid_ref(t01.x), a01y = sigmoid_ref(t01.y);
    float a11x = sigmoid_ref(t11.x), a11y = sigmoid_ref(t11.y);

    float omfu = 1.0f - fu, omfv = 1.0f - fv;
    float kx = (a00x * omfu + a10x * fu) * omfv
             + (a01x * omfu + a11x * fu) * fv;
    float ky = (a00y * omfu + a10y * fu) * omfv
             + (a01y * omfu + a11y * fu) * fv;

    float fU0 = (float)U0;
    float su2 = mul_rn_nocontract(kx, fU0);
    float sv2 = mul_rn_nocontract(ky, fU0);
    float u0f2 = floorf(su2), v0f2 = floorf(sv2);
    float fu2 = su2 - u0f2, fv2 = sv2 - v0f2;
    int p0 = (int)u0f2 % U0; if (p0 < 0) p0 += U0;
    int q0 = (int)v0f2 % U0; if (q0 < 0) q0 += U0;
    int p1 = p0 + 1; if (p1 >= U0) p1 = 0;
    int q1 = q0 + 1; if (q1 >= U0) q1 = 0;
    int b00 = (p0 * U0 + q0) * 3, b10 = (p1 * U0 + q0) * 3;
    int b01 = (p0 * U0 + q1) * 3, b11 = (p1 * U0 + q1) * 3;
    float omfu2 = 1.0f - fu2, omfv2 = 1.0f - fv2;
    float r0 = (s0[b00+0] * omfu2 + s0[b10+0] * fu2) * omfv2
             + (s0[b01+0] * omfu2 + s0[b11+0] * fu2) * fv2;
    float r1 = (s0[b00+1] * omfu2 + s0[b10+1] * fu2) * omfv2
             + (s0[b01+1] * omfu2 + s0[b11+1] * fu2) * fv2;
    float r2 = (s0[b00+2] * omfu2 + s0[b10+2] * fu2) * omfv2
             + (s0[b01+2] * omfu2 + s0[b11+2] * fu2) * fv2;
    out[3*i+0] = r0; out[3*i+1] = r1; out[3*i+2] = r2;
}

// ---- Full fallback: all sigmoids in-kernel (ws too small) ----
__global__ void __launch_bounds__(256) query_kernel_fallback(
    const float* __restrict__ x,
    const float* __restrict__ g1,
    const float* __restrict__ g0,
    float* __restrict__ out,
    int N, int U1, int U0)
{
    int i = blockIdx.x * blockDim.x + threadIdx.x;
    if (i >= N) return;
    float2 uv = reinterpret_cast<const float2*>(x)[i];
    float fU1 = (float)U1;
    float su = mul_rn_nocontract(uv.x, fU1);
    float sv = mul_rn_nocontract(uv.y, fU1);
    float u0f = floorf(su), v0f = floorf(sv);
    float fu = su - u0f, fv = sv - v0f;
    int u0 = (int)u0f % U1; if (u0 < 0) u0 += U1;
    int v0 = (int)v0f % U1; if (v0 < 0) v0 += U1;
    int u1 = u0 + 1; if (u1 >= U1) u1 = 0;
    int v1 = v0 + 1; if (v1 >= U1) v1 = 0;
    const float2* g1v = reinterpret_cast<const float2*>(g1);
    float2 t00 = g1v[u0 * U1 + v0];
    float2 t10 = g1v[u1 * U1 + v0];
    float2 t01 = g1v[u0 * U1 + v1];
    float2 t11 = g1v[u1 * U1 + v1];
    float a00x = sigmoid_ref(t00.x), a00y = sigmoid_ref(t00.y);
    float a10x = sigmoid_ref(t10.x), a10y = sigmoid_ref(t10.y);
    float a01x = sigmoid_ref(t01.x), a01y = sigmoid_ref(t01.y);
    float a11x = sigmoid_ref(t11.x), a11y = sigmoid_ref(t11.y);
    float omfu = 1.0f - fu, omfv = 1.0f - fv;
    float kx = (a00x * omfu + a10x * fu) * omfv + (a01x * omfu + a11x * fu) * fv;
    float ky = (a00y * omfu + a10y * fu) * omfv + (a01y * omfu + a11y * fu) * fv;
    float fU0 = (float)U0;
    float su2 = mul_rn_nocontract(kx, fU0);
    float sv2 = mul_rn_nocontract(ky, fU0);
    float u0f2 = floorf(su2), v0f2 = floorf(sv2);
    float fu2 = su2 - u0f2, fv2 = sv2 - v0f2;
    int p0 = (int)u0f2 % U0; if (p0 < 0) p0 += U0;
    int q0 = (int)v0f2 % U0; if (q0 < 0) q0 += U0;
    int p1 = p0 + 1; if (p1 >= U0) p1 = 0;
    int q1 = q0 + 1; if (q1 >= U0) q1 = 0;
    int b00 = (p0 * U0 + q0) * 3, b10 = (p1 * U0 + q0) * 3;
    int b01 = (p0 * U0 + q1) * 3, b11 = (p1 * U0 + q1) * 3;
    float omfu2 = 1.0f - fu2, omfv2 = 1.0f - fv2;
    float r0 = (sigmoid_ref(g0[b00+0]) * omfu2 + sigmoid_ref(g0[b10+0]) * fu2) * omfv2
             + (sigmoid_ref(g0[b01+0]) * omfu2 + sigmoid_ref(g0[b11+0]) * fu2) * fv2;
    float r1 = (sigmoid_ref(g0[b00+1]) * omfu2 + sigmoid_ref(g0[b10+1]) * fu2) * omfv2
             + (sigmoid_ref(g0[b01+1]) * omfu2 + sigmoid_ref(g0[b11+1]) * fu2) * fv2;
    float r2 = (sigmoid_ref(g0[b00+2]) * omfu2 + sigmoid_ref(g0[b10+2]) * fu2) * omfv2
             + (sigmoid_ref(g0[b01+2]) * omfu2 + sigmoid_ref(g0[b11+2]) * fu2) * fv2;
    out[3*i+0] = r0; out[3*i+1] = r1; out[3*i+2] = r2;
}

extern "C" void kernel_launch(void* const* d_in, const int* in_sizes, int n_in,
                              void* d_out, int out_size, void* d_ws, size_t ws_size,
                              hipStream_t stream) {
    const float* x  = (const float*)d_in[0];
    const float* g1 = (const float*)d_in[1];
    const float* g0 = (const float*)d_in[2];
    float* out = (float*)d_out;

    int N = in_sizes[0] / 2;
    long long n1 = in_sizes[1];          // U1*U1*2
    long long n0 = in_sizes[2];          // U0*U0*3
    int U1 = (int)(sqrt((double)(n1 / 2)) + 0.5);
    int U0 = (int)(sqrt((double)(n0 / 3)) + 0.5);
    long long ncells1 = (long long)U1 * U1;

    int block = 256;
    size_t need_packed = ((size_t)ncells1 * 8 + (size_t)n0) * sizeof(float);
    size_t need_s0     = (size_t)n0 * sizeof(float);

    if (ws_size >= need_packed && (n0 % 4) == 0) {
        float* pk = (float*)d_ws;                     // 138.4 MB packed
        float* s0 = pk + ncells1 * 8;                 // 3.2 MB sigmoided g0
        int n0_4 = (int)(n0 / 4);
        dim3 pgrid((U1 + block - 1) / block, U1);
        pack_fused_kernel<<<pgrid, block, 0, stream>>>(g1, pk, U1);
        sigmoid_table_kernel<<<(n0_4 + block - 1) / block, block, 0, stream>>>(
            (const float4*)g0, (float4*)s0, n0_4);
        query_packed_kernel<<<(N + block - 1) / block, block, 0, stream>>>(
            x, pk, s0, out, N, U1, U0);
    } else if (ws_size >= need_s0 && (n0 % 4) == 0) {
        float* s0 = (float*)d_ws;                     // 3.2 MB sigmoided g0
        int n0_4 = (int)(n0 / 4);
        sigmoid_table_kernel<<<(n0_4 + block - 1) / block, block, 0, stream>>>(
            (const float4*)g0, (float4*)s0, n0_4);
        query_direct_kernel<<<(N + block - 1) / block, block, 0, stream>>>(
            x, g1, s0, out, N, U1, U0);
    } else {
        query_kernel_fallback<<<(N + block - 1) / block, block, 0, stream>>>(
            x, g1, g0, out, N, U1, U0);
    }
}

// Round 8
// 268.750 us; speedup vs baseline: 1.0789x; 1.0280x over previous
//
#include <hip/hip_runtime.h>
#include <math.h>

// Chained bilinear lookup: out = bilinear(grid0, bilinear(grid1, x)),
// sigmoid per corner sample (both stages).
//
// Shapes: x (N,2) f32; grid1 (U1,U1,2) f32, U1=2080; grid0 (U0,U0,3) f32,
// U0=520; out (N,3) f32.
//
// PRECISION CONTRACT (R0-R18, passing at absmax 3.9e-3 / thr 1.96e-2):
//  - su = x*U must be a SINGLE f32 rounded mul (inline-asm v_mul_f32).
//  - Sigmoid: e = expf(-t) f32, then 1/(1+e) in f64 rounded once.
//  - f32 blends as written. Moving sigmoid between pack and query is
//    value-identical. 2pt/thread = identical per-point ops.
//
// COST MODEL: dur_us = kernels + ~88us FIXED harness overhead.
// CACHE MODEL (revised R18): FETCH_SIZE counts L2-miss traffic served
// by L3 OR HBM. Plain-stored workspace tables stay L3-resident ->
// lower service latency. nt stores push them to HBM.
//   query_packed + plain-stored pk: 123.7us (R11/R15, 4x reproduced)
//   query_packed + nt-stored pk:    142us   (R18) => nt pk costs 18us
//   => PLAIN stores for pk always (nt pack gain 16 < query loss 18).
//   query_direct (4 indep loads/thread): 3.54 TB/s
//   query_packed (2 indep loads/thread): 2.99 TB/s
//   => latency/MLP-bound (VALUBusy 13%, occ 80%, VGPR 16): issue width
//      per thread is the limiter, not BW.
//
// PERF HISTORY (key A/Bs):
//  R14: nt LOADS in query: -41%. NEVER.
//  R16: in-query sigmoids ~free. rowpair total 251.8 (best so far).
//  R17: "pre-pass floor" refuted — fixed 88us overhead. direct=197us.
//  R18: nt pk stores slow query 18us (see cache model). REVERT to plain.
//  R19 (this): fused-PLAIN pack + 2pt/thread query (R9 retry, restructured:
//      one 16B x-load, both coord calcs, ALL 4 cell loads issued
//      back-to-back, then blends — mirrors query_direct's 4-indep-load
//      shape that measured 3.54TB/s). Predict query 90-110us @ >=3.3TB/s,
//      pack 44, total 230-245. If query ~124: compiler serialized
//      (check VGPR); if >=140: R9-mode fail -> revert.

typedef float f32x2 __attribute__((ext_vector_type(2)));
typedef float f32x4 __attribute__((ext_vector_type(4)));

__device__ __forceinline__ float mul_rn_nocontract(float a, float b) {
    float r;
    asm("v_mul_f32 %0, %1, %2" : "=v"(r) : "v"(a), "v"(b));
    return r;
}

// ~1-ulp sigmoid matching numpy's f32 chain.
__device__ __forceinline__ float sigmoid_ref(float t) {
    float e = expf(-t);                      // ocml expf, ~1 ulp f32
    return (float)(1.0 / (1.0 + (double)e)); // exact add+div, one rounding
}

// ---- Phase A1: fused corner-pack of grid1 (barrier-free, PLAIN stores) ----
// pk cell (u,v) = [s(t00).xy s(t01).xy | s(t10).xy s(t11).xy]  (32B)
// Plain stores keep pk L3-resident for the query (R18: nt here costs the
// query +18us, more than the 16us it saves the pack).
__global__ void __launch_bounds__(256) pack_fused_kernel(
    const float* __restrict__ g1, float* __restrict__ pk, int U1)
{
    int v = blockIdx.x * 256 + threadIdx.x;
    int u = blockIdx.y;
    if (v >= U1) return;
    int v1 = v + 1; if (v1 >= U1) v1 = 0;
    int u1 = u + 1; if (u1 >= U1) u1 = 0;

    const f32x2* g = reinterpret_cast<const f32x2*>(g1);
    size_t ru0 = (size_t)u  * U1;
    size_t ru1 = (size_t)u1 * U1;
    f32x2 t00 = g[ru0 + v];
    f32x2 t01 = g[ru0 + v1];
    f32x2 t10 = g[ru1 + v];
    f32x2 t11 = g[ru1 + v1];

    f32x4 lo, hi;
    lo.x = sigmoid_ref(t00.x); lo.y = sigmoid_ref(t00.y);
    lo.z = sigmoid_ref(t01.x); lo.w = sigmoid_ref(t01.y);
    hi.x = sigmoid_ref(t10.x); hi.y = sigmoid_ref(t10.y);
    hi.z = sigmoid_ref(t11.x); hi.w = sigmoid_ref(t11.y);

    f32x4* o = reinterpret_cast<f32x4*>(pk + (ru0 + v) * 8);
    o[0] = lo;
    o[1] = hi;
}

// ---- Phase A2: elementwise sigmoid of a table (float4-vectorized) ----
__global__ void __launch_bounds__(256) sigmoid_table_kernel(
    const float4* __restrict__ in, float4* __restrict__ out, int n4)
{
    int i = blockIdx.x * blockDim.x + threadIdx.x;
    if (i >= n4) return;
    float4 v = in[i];
    float4 r;
    r.x = sigmoid_ref(v.x);
    r.y = sigmoid_ref(v.y);
    r.z = sigmoid_ref(v.z);
    r.w = sigmoid_ref(v.w);
    out[i] = r;
}

// ---- Phase B: 2pt/thread packed query (MLP-widened R8 shape) ----
// Straight-line structure: 1x 16B x-load -> both coord calcs -> ALL 4
// cell loads -> both stage-1 blends -> both stage-2 phases (24 indep s0
// loads) -> 6 contiguous out stores.
__global__ void __launch_bounds__(256) query_packed2_kernel(
    const float* __restrict__ x,
    const float* __restrict__ pk,   // packed corners, U1*U1*8 floats
    const float* __restrict__ s0,   // sigmoid(grid0), (U0,U0,3)
    float* __restrict__ out,        // (N,3)
    int N, int U1, int U0)
{
    int t = blockIdx.x * blockDim.x + threadIdx.x;
    int i0 = t * 2;
    if (i0 >= N) return;
    bool has2 = (i0 + 1) < N;

    f32x4 xv;
    if (has2) {
        xv = __builtin_nontemporal_load(
            reinterpret_cast<const f32x4*>(x) + t);
    } else {
        f32x2 a = __builtin_nontemporal_load(
            reinterpret_cast<const f32x2*>(x) + i0);
        xv.x = a.x; xv.y = a.y; xv.z = a.x; xv.w = a.y;
    }

    float fU1 = (float)U1;
    // point 0 coords
    float suA = mul_rn_nocontract(xv.x, fU1);
    float svA = mul_rn_nocontract(xv.y, fU1);
    float u0fA = floorf(suA), v0fA = floorf(svA);
    float fuA = suA - u0fA, fvA = svA - v0fA;
    int u0A = (int)u0fA % U1; if (u0A < 0) u0A += U1;
    int v0A = (int)v0fA % U1; if (v0A < 0) v0A += U1;
    // point 1 coords
    float suB = mul_rn_nocontract(xv.z, fU1);
    float svB = mul_rn_nocontract(xv.w, fU1);
    float u0fB = floorf(suB), v0fB = floorf(svB);
    float fuB = suB - u0fB, fvB = svB - v0fB;
    int u0B = (int)u0fB % U1; if (u0B < 0) u0B += U1;
    int v0B = (int)v0fB % U1; if (v0B < 0) v0B += U1;

    // all 4 cell loads issued back-to-back (plain: pk is L3-resident)
    const float4* cellA = reinterpret_cast<const float4*>(pk)
                        + (size_t)(u0A * U1 + v0A) * 2;
    const float4* cellB = reinterpret_cast<const float4*>(pk)
                        + (size_t)(u0B * U1 + v0B) * 2;
    float4 loA = cellA[0];
    float4 hiA = cellA[1];
    float4 loB = cellB[0];
    float4 hiB = cellB[1];

    // stage-1 blends
    float omfuA = 1.0f - fuA, omfvA = 1.0f - fvA;
    float kxA = (loA.x * omfuA + hiA.x * fuA) * omfvA
              + (loA.z * omfuA + hiA.z * fuA) * fvA;
    float kyA = (loA.y * omfuA + hiA.y * fuA) * omfvA
              + (loA.w * omfuA + hiA.w * fuA) * fvA;
    float omfuB = 1.0f - fuB, omfvB = 1.0f - fvB;
    float kxB = (loB.x * omfuB + hiB.x * fuB) * omfvB
              + (loB.z * omfuB + hiB.z * fuB) * fvB;
    float kyB = (loB.y * omfuB + hiB.y * fuB) * omfvB
              + (loB.w * omfuB + hiB.w * fuB) * fvB;

    // stage-2 addresses for both points
    float fU0 = (float)U0;
    float su2A = mul_rn_nocontract(kxA, fU0);
    float sv2A = mul_rn_nocontract(kyA, fU0);
    float u0f2A = floorf(su2A), v0f2A = floorf(sv2A);
    float fu2A = su2A - u0f2A, fv2A = sv2A - v0f2A;
    int p0A = (int)u0f2A % U0; if (p0A < 0) p0A += U0;
    int q0A = (int)v0f2A % U0; if (q0A < 0) q0A += U0;
    int p1A = p0A + 1; if (p1A >= U0) p1A = 0;
    int q1A = q0A + 1; if (q1A >= U0) q1A = 0;
    int b00A = (p0A * U0 + q0A) * 3, b10A = (p1A * U0 + q0A) * 3;
    int b01A = (p0A * U0 + q1A) * 3, b11A = (p1A * U0 + q1A) * 3;

    float su2B = mul_rn_nocontract(kxB, fU0);
    float sv2B = mul_rn_nocontract(kyB, fU0);
    float u0f2B = floorf(su2B), v0f2B = floorf(sv2B);
    float fu2B = su2B - u0f2B, fv2B = sv2B - v0f2B;
    int p0B = (int)u0f2B % U0; if (p0B < 0) p0B += U0;
    int q0B = (int)v0f2B % U0; if (q0B < 0) q0B += U0;
    int p1B = p0B + 1; if (p1B >= U0) p1B = 0;
    int q1B = q0B + 1; if (q1B >= U0) q1B = 0;
    int b00B = (p0B * U0 + q0B) * 3, b10B = (p1B * U0 + q0B) * 3;
    int b01B = (p0B * U0 + q1B) * 3, b11B = (p1B * U0 + q1B) * 3;

    float omfu2A = 1.0f - fu2A, omfv2A = 1.0f - fv2A;
    float omfu2B = 1.0f - fu2B, omfv2B = 1.0f - fv2B;

    float r0A = (s0[b00A+0] * omfu2A + s0[b10A+0] * fu2A) * omfv2A
              + (s0[b01A+0] * omfu2A + s0[b11A+0] * fu2A) * fv2A;
    float r1A = (s0[b00A+1] * omfu2A + s0[b10A+1] * fu2A) * omfv2A
              + (s0[b01A+1] * omfu2A + s0[b11A+1] * fu2A) * fv2A;
    float r2A = (s0[b00A+2] * omfu2A + s0[b10A+2] * fu2A) * omfv2A
              + (s0[b01A+2] * omfu2A + s0[b11A+2] * fu2A) * fv2A;
    float r0B = (s0[b00B+0] * omfu2B + s0[b10B+0] * fu2B) * omfv2B
              + (s0[b01B+0] * omfu2B + s0[b11B+0] * fu2B) * fv2B;
    float r1B = (s0[b00B+1] * omfu2B + s0[b10B+1] * fu2B) * omfv2B
              + (s0[b01B+1] * omfu2B + s0[b11B+1] * fu2B) * fv2B;
    float r2B = (s0[b00B+2] * omfu2B + s0[b10B+2] * fu2B) * omfv2B
              + (s0[b01B+2] * omfu2B + s0[b11B+2] * fu2B) * fv2B;

    out[3*i0+0] = r0A; out[3*i0+1] = r1A; out[3*i0+2] = r2A;
    if (has2) {
        out[3*i0+3] = r0B; out[3*i0+4] = r1B; out[3*i0+5] = r2B;
    }
}

// ---- Middle variant: direct query, no grid1 pre-pass (R17, 197us) ----
__global__ void __launch_bounds__(256) query_direct_kernel(
    const float* __restrict__ x,
    const float* __restrict__ g1,
    const float* __restrict__ s0,
    float* __restrict__ out,
    int N, int U1, int U0)
{
    int i = blockIdx.x * blockDim.x + threadIdx.x;
    if (i >= N) return;

    f32x2 uv = __builtin_nontemporal_load(
        reinterpret_cast<const f32x2*>(x) + i);

    float fU1 = (float)U1;
    float su = mul_rn_nocontract(uv.x, fU1);
    float sv = mul_rn_nocontract(uv.y, fU1);
    float u0f = floorf(su), v0f = floorf(sv);
    float fu = su - u0f, fv = sv - v0f;
    int u0 = (int)u0f % U1; if (u0 < 0) u0 += U1;
    int v0 = (int)v0f % U1; if (v0 < 0) v0 += U1;
    int u1 = u0 + 1; if (u1 >= U1) u1 = 0;
    int v1 = v0 + 1; if (v1 >= U1) v1 = 0;

    const f32x2* g = reinterpret_cast<const f32x2*>(g1);
    const f32x2* row0 = g + (size_t)u0 * U1;
    const f32x2* row1 = g + (size_t)u1 * U1;
    f32x2 t00 = row0[v0];
    f32x2 t01 = row0[v1];
    f32x2 t10 = row1[v0];
    f32x2 t11 = row1[v1];

    float a00x = sigmoid_ref(t00.x), a00y = sigmoid_ref(t00.y);
    float a10x = sigmoid_ref(t10.x), a10y = sigmoid_ref(t10.y);
    float a01x = sigmoid_ref(t01.x), a01y = sigmoid_ref(t01.y);
    float a11x = sigmoid_ref(t11.x), a11y = sigmoid_ref(t11.y);

    float omfu = 1.0f - fu, omfv = 1.0f - fv;
    float kx = (a00x * omfu + a10x * fu) * omfv
             + (a01x * omfu + a11x * fu) * fv;
    float ky = (a00y * omfu + a10y * fu) * omfv
             + (a01y * omfu + a11y * fu) * fv;

    float fU0 = (float)U0;
    float su2 = mul_rn_nocontract(kx, fU0);
    float sv2 = mul_rn_nocontract(ky, fU0);
    float u0f2 = floorf(su2), v0f2 = floorf(sv2);
    float fu2 = su2 - u0f2, fv2 = sv2 - v0f2;
    int p0 = (int)u0f2 % U0; if (p0 < 0) p0 += U0;
    int q0 = (int)v0f2 % U0; if (q0 < 0) q0 += U0;
    int p1 = p0 + 1; if (p1 >= U0) p1 = 0;
    int q1 = q0 + 1; if (q1 >= U0) q1 = 0;
    int b00 = (p0 * U0 + q0) * 3, b10 = (p1 * U0 + q0) * 3;
    int b01 = (p0 * U0 + q1) * 3, b11 = (p1 * U0 + q1) * 3;
    float omfu2 = 1.0f - fu2, omfv2 = 1.0f - fv2;
    float r0 = (s0[b00+0] * omfu2 + s0[b10+0] * fu2) * omfv2
             + (s0[b01+0] * omfu2 + s0[b11+0] * fu2) * fv2;
    float r1 = (s0[b00+1] * omfu2 + s0[b10+1] * fu2) * omfv2
             + (s0[b01+1] * omfu2 + s0[b11+1] * fu2) * fv2;
    float r2 = (s0[b00+2] * omfu2 + s0[b10+2] * fu2) * omfv2
             + (s0[b01+2] * omfu2 + s0[b11+2] * fu2) * fv2;
    out[3*i+0] = r0; out[3*i+1] = r1; out[3*i+2] = r2;
}

// ---- Full fallback: all sigmoids in-kernel (ws too small) ----
__global__ void __launch_bounds__(256) query_kernel_fallback(
    const float* __restrict__ x,
    const float* __restrict__ g1,
    const float* __restrict__ g0,
    float* __restrict__ out,
    int N, int U1, int U0)
{
    int i = blockIdx.x * blockDim.x + threadIdx.x;
    if (i >= N) return;
    float2 uv = reinterpret_cast<const float2*>(x)[i];
    float fU1 = (float)U1;
    float su = mul_rn_nocontract(uv.x, fU1);
    float sv = mul_rn_nocontract(uv.y, fU1);
    float u0f = floorf(su), v0f = floorf(sv);
    float fu = su - u0f, fv = sv - v0f;
    int u0 = (int)u0f % U1; if (u0 < 0) u0 += U1;
    int v0 = (int)v0f % U1; if (v0 < 0) v0 += U1;
    int u1 = u0 + 1; if (u1 >= U1) u1 = 0;
    int v1 = v0 + 1; if (v1 >= U1) v1 = 0;
    const float2* g1v = reinterpret_cast<const float2*>(g1);
    float2 t00 = g1v[u0 * U1 + v0];
    float2 t10 = g1v[u1 * U1 + v0];
    float2 t01 = g1v[u0 * U1 + v1];
    float2 t11 = g1v[u1 * U1 + v1];
    float a00x = sigmoid_ref(t00.x), a00y = sigmoid_ref(t00.y);
    float a10x = sigmoid_ref(t10.x), a10y = sigmoid_ref(t10.y);
    float a01x = sigmoid_ref(t01.x), a01y = sigmoid_ref(t01.y);
    float a11x = sigmoid_ref(t11.x), a11y = sigmoid_ref(t11.y);
    float omfu = 1.0f - fu, omfv = 1.0f - fv;
    float kx = (a00x * omfu + a10x * fu) * omfv + (a01x * omfu + a11x * fu) * fv;
    float ky = (a00y * omfu + a10y * fu) * omfv + (a01y * omfu + a11y * fu) * fv;
    float fU0 = (float)U0;
    float su2 = mul_rn_nocontract(kx, fU0);
    float sv2 = mul_rn_nocontract(ky, fU0);
    float u0f2 = floorf(su2), v0f2 = floorf(sv2);
    float fu2 = su2 - u0f2, fv2 = sv2 - v0f2;
    int p0 = (int)u0f2 % U0; if (p0 < 0) p0 += U0;
    int q0 = (int)v0f2 % U0; if (q0 < 0) q0 += U0;
    int p1 = p0 + 1; if (p1 >= U0) p1 = 0;
    int q1 = q0 + 1; if (q1 >= U0) q1 = 0;
    int b00 = (p0 * U0 + q0) * 3, b10 = (p1 * U0 + q0) * 3;
    int b01 = (p0 * U0 + q1) * 3, b11 = (p1 * U0 + q1) * 3;
    float omfu2 = 1.0f - fu2, omfv2 = 1.0f - fv2;
    float r0 = (sigmoid_ref(g0[b00+0]) * omfu2 + sigmoid_ref(g0[b10+0]) * fu2) * omfv2
             + (sigmoid_ref(g0[b01+0]) * omfu2 + sigmoid_ref(g0[b11+0]) * fu2) * fv2;
    float r1 = (sigmoid_ref(g0[b00+1]) * omfu2 + sigmoid_ref(g0[b10+1]) * fu2) * omfv2
             + (sigmoid_ref(g0[b01+1]) * omfu2 + sigmoid_ref(g0[b11+1]) * fu2) * fv2;
    float r2 = (sigmoid_ref(g0[b00+2]) * omfu2 + sigmoid_ref(g0[b10+2]) * fu2) * omfv2
             + (sigmoid_ref(g0[b01+2]) * omfu2 + sigmoid_ref(g0[b11+2]) * fu2) * fv2;
    out[3*i+0] = r0; out[3*i+1] = r1; out[3*i+2] = r2;
}

extern "C" void kernel_launch(void* const* d_in, const int* in_sizes, int n_in,
                              void* d_out, int out_size, void* d_ws, size_t ws_size,
                              hipStream_t stream) {
    const float* x  = (const float*)d_in[0];
    const float* g1 = (const float*)d_in[1];
    const float* g0 = (const float*)d_in[2];
    float* out = (float*)d_out;

    int N = in_sizes[0] / 2;
    long long n1 = in_sizes[1];          // U1*U1*2
    long long n0 = in_sizes[2];          // U0*U0*3
    int U1 = (int)(sqrt((double)(n1 / 2)) + 0.5);
    int U0 = (int)(sqrt((double)(n0 / 3)) + 0.5);
    long long ncells1 = (long long)U1 * U1;

    int block = 256;
    size_t need_packed = ((size_t)ncells1 * 8 + (size_t)n0) * sizeof(float);
    size_t need_s0     = (size_t)n0 * sizeof(float);

    if (ws_size >= need_packed && (n0 % 4) == 0) {
        float* pk = (float*)d_ws;                     // 138.4 MB packed
        float* s0 = pk + ncells1 * 8;                 // 3.2 MB sigmoided g0
        int n0_4 = (int)(n0 / 4);
        dim3 pgrid((U1 + block - 1) / block, U1);
        pack_fused_kernel<<<pgrid, block, 0, stream>>>(g1, pk, U1);
        sigmoid_table_kernel<<<(n0_4 + block - 1) / block, block, 0, stream>>>(
            (const float4*)g0, (float4*)s0, n0_4);
        int npair = (N + 1) / 2;
        query_packed2_kernel<<<(npair + block - 1) / block, block, 0, stream>>>(
            x, pk, s0, out, N, U1, U0);
    } else if (ws_size >= need_s0 && (n0 % 4) == 0) {
        float* s0 = (float*)d_ws;                     // 3.2 MB sigmoided g0
        int n0_4 = (int)(n0 / 4);
        sigmoid_table_kernel<<<(n0_4 + block - 1) / block, block, 0, stream>>>(
            (const float4*)g0, (float4*)s0, n0_4);
        query_direct_kernel<<<(N + block - 1) / block, block, 0, stream>>>(
            x, g1, s0, out, N, U1, U0);
    } else {
        query_kernel_fallback<<<(N + block - 1) / block, block, 0, stream>>>(
            x, g1, g0, out, N, U1, U0);
    }
}

// Round 9
// 260.336 us; speedup vs baseline: 1.1137x; 1.0323x over previous
//
#include <hip/hip_runtime.h>
#include <math.h>

// Chained bilinear lookup: out = bilinear(grid0, bilinear(grid1, x)),
// sigmoid per corner sample (both stages).
//
// Shapes: x (N,2) f32; grid1 (U1,U1,2) f32, U1=2080; grid0 (U0,U0,3) f32,
// U0=520; out (N,3) f32.
//
// PRECISION CONTRACT (R0-R19, passing at absmax 3.9e-3 / thr 1.96e-2):
//  - su = x*U must be a SINGLE f32 rounded mul (inline-asm v_mul_f32).
//  - Sigmoid: e = expf(-t) f32, then 1/(1+e) in f64 rounded once.
//  - f32 blends as written. Multi-point/thread = identical per-point ops.
//
// COST MODEL: dur_us = kernels + ~88us FIXED harness overhead.
// CACHE/LATENCY MODEL (R18/R19):
//  - FETCH_SIZE counts L2-miss traffic (L3- or HBM-served). Plain-stored
//    workspace stays L3-resident; nt stores push to HBM: query on
//    nt-stored pk = 142us vs plain 123.7us. PLAIN pack stores always.
//  - Query is line-THROUGHPUT bound (VALUBusy 13%, lines-in-flight x
//    latency): direct (2 indep lines/pt) = 3.54TB/s vs packed (1
//    line/pt) = 2.99TB/s.
//  - R19 2pt/thread contiguous: 24B/thread stores broke write
//    coalescing (WRITE 49->88MB, +13us). dur 138. Per-point 12B
//    wave-contiguous stores are clean.
//
// PERF HISTORY (key A/Bs):
//  R14: nt LOADS in query: -41%. NEVER.
//  R15: plain fused pack 44us + query_packed 123.7 + sig 4 -> 260.4.
//  R16: rowpair(nt) 18 + query_rowpair 141 + 4 -> 251.8 (best total).
//  R17: fixed-88us overhead discovered; direct query 197us.
//  R18: nt pk stores cost query +18us. R19: write amplification.
//  R20 (this): 2pt/thread STRIDED (t, t+N/2): two indep cell-line
//      fetches (MLP of direct) + clean 12B-per-point stores (coalescing
//      of 1pt/thread). Only change vs R15 = query shape.
//      Predict WRITE ~49MB, FETCH ~312MB; query 100-112us if MLP real
//      (total ~236-248), ~124 if neutral, >130 refutes -> revert.

typedef float f32x2 __attribute__((ext_vector_type(2)));
typedef float f32x4 __attribute__((ext_vector_type(4)));

__device__ __forceinline__ float mul_rn_nocontract(float a, float b) {
    float r;
    asm("v_mul_f32 %0, %1, %2" : "=v"(r) : "v"(a), "v"(b));
    return r;
}

// ~1-ulp sigmoid matching numpy's f32 chain.
__device__ __forceinline__ float sigmoid_ref(float t) {
    float e = expf(-t);                      // ocml expf, ~1 ulp f32
    return (float)(1.0 / (1.0 + (double)e)); // exact add+div, one rounding
}

// ---- Phase A1: fused corner-pack of grid1 (barrier-free, PLAIN stores) ----
// pk cell (u,v) = [s(t00).xy s(t01).xy | s(t10).xy s(t11).xy]  (32B)
// Plain stores keep pk L3-resident for the query (R18: nt costs query
// +18us > the 16us it saves here).
__global__ void __launch_bounds__(256) pack_fused_kernel(
    const float* __restrict__ g1, float* __restrict__ pk, int U1)
{
    int v = blockIdx.x * 256 + threadIdx.x;
    int u = blockIdx.y;
    if (v >= U1) return;
    int v1 = v + 1; if (v1 >= U1) v1 = 0;
    int u1 = u + 1; if (u1 >= U1) u1 = 0;

    const f32x2* g = reinterpret_cast<const f32x2*>(g1);
    size_t ru0 = (size_t)u  * U1;
    size_t ru1 = (size_t)u1 * U1;
    f32x2 t00 = g[ru0 + v];
    f32x2 t01 = g[ru0 + v1];
    f32x2 t10 = g[ru1 + v];
    f32x2 t11 = g[ru1 + v1];

    f32x4 lo, hi;
    lo.x = sigmoid_ref(t00.x); lo.y = sigmoid_ref(t00.y);
    lo.z = sigmoid_ref(t01.x); lo.w = sigmoid_ref(t01.y);
    hi.x = sigmoid_ref(t10.x); hi.y = sigmoid_ref(t10.y);
    hi.z = sigmoid_ref(t11.x); hi.w = sigmoid_ref(t11.y);

    f32x4* o = reinterpret_cast<f32x4*>(pk + (ru0 + v) * 8);
    o[0] = lo;
    o[1] = hi;
}

// ---- Phase A2: elementwise sigmoid of a table (float4-vectorized) ----
__global__ void __launch_bounds__(256) sigmoid_table_kernel(
    const float4* __restrict__ in, float4* __restrict__ out, int n4)
{
    int i = blockIdx.x * blockDim.x + threadIdx.x;
    if (i >= n4) return;
    float4 v = in[i];
    float4 r;
    r.x = sigmoid_ref(v.x);
    r.y = sigmoid_ref(v.y);
    r.z = sigmoid_ref(v.z);
    r.w = sigmoid_ref(v.w);
    out[i] = r;
}

// ---- Phase B: 2pt/thread STRIDED packed query ----
// Thread t handles points t and t+M (M = ceil(N/2)): two INDEPENDENT
// pk cell-line fetches issued back-to-back (MLP), while each point's
// 12B output store stays wave-contiguous (clean coalescing).
__global__ void __launch_bounds__(256) query_packed2s_kernel(
    const float* __restrict__ x,
    const float* __restrict__ pk,   // packed corners, U1*U1*8 floats
    const float* __restrict__ s0,   // sigmoid(grid0), (U0,U0,3)
    float* __restrict__ out,        // (N,3)
    int N, int M, int U1, int U0)
{
    int t = blockIdx.x * blockDim.x + threadIdx.x;
    if (t >= M) return;
    int iA = t;
    int iB = t + M;
    bool hasB = iB < N;

    f32x2 uvA = __builtin_nontemporal_load(
        reinterpret_cast<const f32x2*>(x) + iA);
    f32x2 uvB = uvA;
    if (hasB) uvB = __builtin_nontemporal_load(
        reinterpret_cast<const f32x2*>(x) + iB);

    float fU1 = (float)U1;
    // point A coords
    float suA = mul_rn_nocontract(uvA.x, fU1);
    float svA = mul_rn_nocontract(uvA.y, fU1);
    float u0fA = floorf(suA), v0fA = floorf(svA);
    float fuA = suA - u0fA, fvA = svA - v0fA;
    int u0A = (int)u0fA % U1; if (u0A < 0) u0A += U1;
    int v0A = (int)v0fA % U1; if (v0A < 0) v0A += U1;
    // point B coords
    float suB = mul_rn_nocontract(uvB.x, fU1);
    float svB = mul_rn_nocontract(uvB.y, fU1);
    float u0fB = floorf(suB), v0fB = floorf(svB);
    float fuB = suB - u0fB, fvB = svB - v0fB;
    int u0B = (int)u0fB % U1; if (u0B < 0) u0B += U1;
    int v0B = (int)v0fB % U1; if (v0B < 0) v0B += U1;

    // both cell loads issued back-to-back (pk L3-resident, plain)
    const float4* cellA = reinterpret_cast<const float4*>(pk)
                        + (size_t)(u0A * U1 + v0A) * 2;
    const float4* cellB = reinterpret_cast<const float4*>(pk)
                        + (size_t)(u0B * U1 + v0B) * 2;
    float4 loA = cellA[0];
    float4 hiA = cellA[1];
    float4 loB = cellB[0];
    float4 hiB = cellB[1];

    // stage-1 blends
    float omfuA = 1.0f - fuA, omfvA = 1.0f - fvA;
    float kxA = (loA.x * omfuA + hiA.x * fuA) * omfvA
              + (loA.z * omfuA + hiA.z * fuA) * fvA;
    float kyA = (loA.y * omfuA + hiA.y * fuA) * omfvA
              + (loA.w * omfuA + hiA.w * fuA) * fvA;
    float omfuB = 1.0f - fuB, omfvB = 1.0f - fvB;
    float kxB = (loB.x * omfuB + hiB.x * fuB) * omfvB
              + (loB.z * omfuB + hiB.z * fuB) * fvB;
    float kyB = (loB.y * omfuB + hiB.y * fuB) * omfvB
              + (loB.w * omfuB + hiB.w * fuB) * fvB;

    // stage-2 addresses for both points
    float fU0 = (float)U0;
    float su2A = mul_rn_nocontract(kxA, fU0);
    float sv2A = mul_rn_nocontract(kyA, fU0);
    float u0f2A = floorf(su2A), v0f2A = floorf(sv2A);
    float fu2A = su2A - u0f2A, fv2A = sv2A - v0f2A;
    int p0A = (int)u0f2A % U0; if (p0A < 0) p0A += U0;
    int q0A = (int)v0f2A % U0; if (q0A < 0) q0A += U0;
    int p1A = p0A + 1; if (p1A >= U0) p1A = 0;
    int q1A = q0A + 1; if (q1A >= U0) q1A = 0;
    int b00A = (p0A * U0 + q0A) * 3, b10A = (p1A * U0 + q0A) * 3;
    int b01A = (p0A * U0 + q1A) * 3, b11A = (p1A * U0 + q1A) * 3;

    float su2B = mul_rn_nocontract(kxB, fU0);
    float sv2B = mul_rn_nocontract(kyB, fU0);
    float u0f2B = floorf(su2B), v0f2B = floorf(sv2B);
    float fu2B = su2B - u0f2B, fv2B = sv2B - v0f2B;
    int p0B = (int)u0f2B % U0; if (p0B < 0) p0B += U0;
    int q0B = (int)v0f2B % U0; if (q0B < 0) q0B += U0;
    int p1B = p0B + 1; if (p1B >= U0) p1B = 0;
    int q1B = q0B + 1; if (q1B >= U0) q1B = 0;
    int b00B = (p0B * U0 + q0B) * 3, b10B = (p1B * U0 + q0B) * 3;
    int b01B = (p0B * U0 + q1B) * 3, b11B = (p1B * U0 + q1B) * 3;

    float omfu2A = 1.0f - fu2A, omfv2A = 1.0f - fv2A;
    float omfu2B = 1.0f - fu2B, omfv2B = 1.0f - fv2B;

    float r0A = (s0[b00A+0] * omfu2A + s0[b10A+0] * fu2A) * omfv2A
              + (s0[b01A+0] * omfu2A + s0[b11A+0] * fu2A) * fv2A;
    float r1A = (s0[b00A+1] * omfu2A + s0[b10A+1] * fu2A) * omfv2A
              + (s0[b01A+1] * omfu2A + s0[b11A+1] * fu2A) * fv2A;
    float r2A = (s0[b00A+2] * omfu2A + s0[b10A+2] * fu2A) * omfv2A
              + (s0[b01A+2] * omfu2A + s0[b11A+2] * fu2A) * fv2A;

    out[3*iA+0] = r0A; out[3*iA+1] = r1A; out[3*iA+2] = r2A;

    if (hasB) {
        float r0B = (s0[b00B+0] * omfu2B + s0[b10B+0] * fu2B) * omfv2B
                  + (s0[b01B+0] * omfu2B + s0[b11B+0] * fu2B) * fv2B;
        float r1B = (s0[b00B+1] * omfu2B + s0[b10B+1] * fu2B) * omfv2B
                  + (s0[b01B+1] * omfu2B + s0[b11B+1] * fu2B) * fv2B;
        float r2B = (s0[b00B+2] * omfu2B + s0[b10B+2] * fu2B) * omfv2B
                  + (s0[b01B+2] * omfu2B + s0[b11B+2] * fu2B) * fv2B;
        out[3*iB+0] = r0B; out[3*iB+1] = r1B; out[3*iB+2] = r2B;
    }
}

// ---- Middle variant: direct query, no grid1 pre-pass (R17, 197us) ----
__global__ void __launch_bounds__(256) query_direct_kernel(
    const float* __restrict__ x,
    const float* __restrict__ g1,
    const float* __restrict__ s0,
    float* __restrict__ out,
    int N, int U1, int U0)
{
    int i = blockIdx.x * blockDim.x + threadIdx.x;
    if (i >= N) return;

    f32x2 uv = __builtin_nontemporal_load(
        reinterpret_cast<const f32x2*>(x) + i);

    float fU1 = (float)U1;
    float su = mul_rn_nocontract(uv.x, fU1);
    float sv = mul_rn_nocontract(uv.y, fU1);
    float u0f = floorf(su), v0f = floorf(sv);
    float fu = su - u0f, fv = sv - v0f;
    int u0 = (int)u0f % U1; if (u0 < 0) u0 += U1;
    int v0 = (int)v0f % U1; if (v0 < 0) v0 += U1;
    int u1 = u0 + 1; if (u1 >= U1) u1 = 0;
    int v1 = v0 + 1; if (v1 >= U1) v1 = 0;

    const f32x2* g = reinterpret_cast<const f32x2*>(g1);
    const f32x2* row0 = g + (size_t)u0 * U1;
    const f32x2* row1 = g + (size_t)u1 * U1;
    f32x2 t00 = row0[v0];
    f32x2 t01 = row0[v1];
    f32x2 t10 = row1[v0];
    f32x2 t11 = row1[v1];

    float a00x = sigmoid_ref(t00.x), a00y = sigmoid_ref(t00.y);
    float a10x = sigmoid_ref(t10.x), a10y = sigmoid_ref(t10.y);
    float a01x = sigmoid_ref(t01.x), a01y = sigmoid_ref(t01.y);
    float a11x = sigmoid_ref(t11.x), a11y = sigmoid_ref(t11.y);

    float omfu = 1.0f - fu, omfv = 1.0f - fv;
    float kx = (a00x * omfu + a10x * fu) * omfv
             + (a01x * omfu + a11x * fu) * fv;
    float ky = (a00y * omfu + a10y * fu) * omfv
             + (a01y * omfu + a11y * fu) * fv;

    float fU0 = (float)U0;
    float su2 = mul_rn_nocontract(kx, fU0);
    float sv2 = mul_rn_nocontract(ky, fU0);
    float u0f2 = floorf(su2), v0f2 = floorf(sv2);
    float fu2 = su2 - u0f2, fv2 = sv2 - v0f2;
    int p0 = (int)u0f2 % U0; if (p0 < 0) p0 += U0;
    int q0 = (int)v0f2 % U0; if (q0 < 0) q0 += U0;
    int p1 = p0 + 1; if (p1 >= U0) p1 = 0;
    int q1 = q0 + 1; if (q1 >= U0) q1 = 0;
    int b00 = (p0 * U0 + q0) * 3, b10 = (p1 * U0 + q0) * 3;
    int b01 = (p0 * U0 + q1) * 3, b11 = (p1 * U0 + q1) * 3;
    float omfu2 = 1.0f - fu2, omfv2 = 1.0f - fv2;
    float r0 = (s0[b00+0] * omfu2 + s0[b10+0] * fu2) * omfv2
             + (s0[b01+0] * omfu2 + s0[b11+0] * fu2) * fv2;
    float r1 = (s0[b00+1] * omfu2 + s0[b10+1] * fu2) * omfv2
             + (s0[b01+1] * omfu2 + s0[b11+1] * fu2) * fv2;
    float r2 = (s0[b00+2] * omfu2 + s0[b10+2] * fu2) * omfv2
             + (s0[b01+2] * omfu2 + s0[b11+2] * fu2) * fv2;
    out[3*i+0] = r0; out[3*i+1] = r1; out[3*i+2] = r2;
}

// ---- Full fallback: all sigmoids in-kernel (ws too small) ----
__global__ void __launch_bounds__(256) query_kernel_fallback(
    const float* __restrict__ x,
    const float* __restrict__ g1,
    const float* __restrict__ g0,
    float* __restrict__ out,
    int N, int U1, int U0)
{
    int i = blockIdx.x * blockDim.x + threadIdx.x;
    if (i >= N) return;
    float2 uv = reinterpret_cast<const float2*>(x)[i];
    float fU1 = (float)U1;
    float su = mul_rn_nocontract(uv.x, fU1);
    float sv = mul_rn_nocontract(uv.y, fU1);
    float u0f = floorf(su), v0f = floorf(sv);
    float fu = su - u0f, fv = sv - v0f;
    int u0 = (int)u0f % U1; if (u0 < 0) u0 += U1;
    int v0 = (int)v0f % U1; if (v0 < 0) v0 += U1;
    int u1 = u0 + 1; if (u1 >= U1) u1 = 0;
    int v1 = v0 + 1; if (v1 >= U1) v1 = 0;
    const float2* g1v = reinterpret_cast<const float2*>(g1);
    float2 t00 = g1v[u0 * U1 + v0];
    float2 t10 = g1v[u1 * U1 + v0];
    float2 t01 = g1v[u0 * U1 + v1];
    float2 t11 = g1v[u1 * U1 + v1];
    float a00x = sigmoid_ref(t00.x), a00y = sigmoid_ref(t00.y);
    float a10x = sigmoid_ref(t10.x), a10y = sigmoid_ref(t10.y);
    float a01x = sigmoid_ref(t01.x), a01y = sigmoid_ref(t01.y);
    float a11x = sigmoid_ref(t11.x), a11y = sigmoid_ref(t11.y);
    float omfu = 1.0f - fu, omfv = 1.0f - fv;
    float kx = (a00x * omfu + a10x * fu) * omfv + (a01x * omfu + a11x * fu) * fv;
    float ky = (a00y * omfu + a10y * fu) * omfv + (a01y * omfu + a11y * fu) * fv;
    float fU0 = (float)U0;
    float su2 = mul_rn_nocontract(kx, fU0);
    float sv2 = mul_rn_nocontract(ky, fU0);
    float u0f2 = floorf(su2), v0f2 = floorf(sv2);
    float fu2 = su2 - u0f2, fv2 = sv2 - v0f2;
    int p0 = (int)u0f2 % U0; if (p0 < 0) p0 += U0;
    int q0 = (int)v0f2 % U0; if (q0 < 0) q0 += U0;
    int p1 = p0 + 1; if (p1 >= U0) p1 = 0;
    int q1 = q0 + 1; if (q1 >= U0) q1 = 0;
    int b00 = (p0 * U0 + q0) * 3, b10 = (p1 * U0 + q0) * 3;
    int b01 = (p0 * U0 + q1) * 3, b11 = (p1 * U0 + q1) * 3;
    float omfu2 = 1.0f - fu2, omfv2 = 1.0f - fv2;
    float r0 = (sigmoid_ref(g0[b00+0]) * omfu2 + sigmoid_ref(g0[b10+0]) * fu2) * omfv2
             + (sigmoid_ref(g0[b01+0]) * omfu2 + sigmoid_ref(g0[b11+0]) * fu2) * fv2;
    float r1 = (sigmoid_ref(g0[b00+1]) * omfu2 + sigmoid_ref(g0[b10+1]) * fu2) * omfv2
             + (sigmoid_ref(g0[b01+1]) * omfu2 + sigmoid_ref(g0[b11+1]) * fu2) * fv2;
    float r2 = (sigmoid_ref(g0[b00+2]) * omfu2 + sigmoid_ref(g0[b10+2]) * fu2) * omfv2
             + (sigmoid_ref(g0[b01+2]) * omfu2 + sigmoid_ref(g0[b11+2]) * fu2) * fv2;
    out[3*i+0] = r0; out[3*i+1] = r1; out[3*i+2] = r2;
}

extern "C" void kernel_launch(void* const* d_in, const int* in_sizes, int n_in,
                              void* d_out, int out_size, void* d_ws, size_t ws_size,
                              hipStream_t stream) {
    const float* x  = (const float*)d_in[0];
    const float* g1 = (const float*)d_in[1];
    const float* g0 = (const float*)d_in[2];
    float* out = (float*)d_out;

    int N = in_sizes[0] / 2;
    long long n1 = in_sizes[1];          // U1*U1*2
    long long n0 = in_sizes[2];          // U0*U0*3
    int U1 = (int)(sqrt((double)(n1 / 2)) + 0.5);
    int U0 = (int)(sqrt((double)(n0 / 3)) + 0.5);
    long long ncells1 = (long long)U1 * U1;

    int block = 256;
    size_t need_packed = ((size_t)ncells1 * 8 + (size_t)n0) * sizeof(float);
    size_t need_s0     = (size_t)n0 * sizeof(float);

    if (ws_size >= need_packed && (n0 % 4) == 0) {
        float* pk = (float*)d_ws;                     // 138.4 MB packed
        float* s0 = pk + ncells1 * 8;                 // 3.2 MB sigmoided g0
        int n0_4 = (int)(n0 / 4);
        dim3 pgrid((U1 + block - 1) / block, U1);
        pack_fused_kernel<<<pgrid, block, 0, stream>>>(g1, pk, U1);
        sigmoid_table_kernel<<<(n0_4 + block - 1) / block, block, 0, stream>>>(
            (const float4*)g0, (float4*)s0, n0_4);
        int M = (N + 1) / 2;
        query_packed2s_kernel<<<(M + block - 1) / block, block, 0, stream>>>(
            x, pk, s0, out, N, M, U1, U0);
    } else if (ws_size >= need_s0 && (n0 % 4) == 0) {
        float* s0 = (float*)d_ws;                     // 3.2 MB sigmoided g0
        int n0_4 = (int)(n0 / 4);
        sigmoid_table_kernel<<<(n0_4 + block - 1) / block, block, 0, stream>>>(
            (const float4*)g0, (float4*)s0, n0_4);
        query_direct_kernel<<<(N + block - 1) / block, block, 0, stream>>>(
            x, g1, s0, out, N, U1, U0);
    } else {
        query_kernel_fallback<<<(N + block - 1) / block, block, 0, stream>>>(
            x, g1, g0, out, N, U1, U0);
    }
}

// Round 10
// 249.856 us; speedup vs baseline: 1.1604x; 1.0419x over previous
//
#include <hip/hip_runtime.h>
#include <math.h>

// Chained bilinear lookup: out = bilinear(grid0, bilinear(grid1, x)),
// sigmoid per corner sample (both stages).
//
// Shapes: x (N,2) f32; grid1 (U1,U1,2) f32, U1=2080; grid0 (U0,U0,3) f32,
// U0=520; out (N,3) f32.
//
// PRECISION CONTRACT (R0-R20, passing at absmax 3.9e-3 / thr 1.96e-2):
//  - su = x*U must be a SINGLE f32 rounded mul (inline-asm v_mul_f32).
//  - Sigmoid: e = expf(-t) f32, then 1/(1+e) in f64 rounded once.
//  - f32 blends as written. Vector-loading the SAME s0 floats is
//    value-identical (layout of loads only).
//
// COST MODEL: dur_us = kernels + ~88us FIXED harness overhead.
// TRANSACTION MODEL (R20): query is memory-pipe TRANSACTION-bound:
// address-divergent loads cost ~1 slot per active lane. packed query
// per wave: pk 128 + s0 768 (12 scalar loads!) + misc 24 ~= 920 slots
// -> 98us predicted, 124 measured. Direct kernel is instead
// line-service-bound (600MB @ 3.04TB/s = 197us). MLP per thread is NOT
// the limiter (R19/R20: packed2s == packed at same transactions/pt).
// CACHE MODEL (R18): plain-stored ws tables stay L3-resident; nt stores
// push to HBM (query on nt pk = 142 vs 124). PLAIN pack stores. nt
// LOADS in query: -41% (R14). NEVER.
//
// PERF HISTORY (key A/Bs):
//  R15: plain fused pack 44 + query_packed 123.7 + sig 4 -> 260.4.
//  R16: rowpair total 251.8 (prev best). R17: direct 197; 88us found.
//  R18: nt pk stores +18us query. R19: 24B/thread stores broke write
//       coalescing (+13us). R20: strided 2pt/thread = 124 (MLP null).
//  R21 (this): stage-2 s0 loads 12 -> 4 per point: the two 6-float
//      row segments (texels (p,q0),(p,q0+1) contiguous in AoS, 24B)
//      loaded as align-4 f32x4 + f32x2 (gfx950 unaligned global OK);
//      wrap q1==0 (0.2% pts) takes old scalar path. Same lines, same
//      values, same blend order. Predict query 85-110us (FETCH ~312MB,
//      WRITE 49MB), total 225-245. If ~124: model refuted -> pivot.

typedef float f32x2 __attribute__((ext_vector_type(2)));
typedef float f32x4 __attribute__((ext_vector_type(4)));
typedef float f32x4u __attribute__((ext_vector_type(4), aligned(4)));
typedef float f32x2u __attribute__((ext_vector_type(2), aligned(4)));

__device__ __forceinline__ float mul_rn_nocontract(float a, float b) {
    float r;
    asm("v_mul_f32 %0, %1, %2" : "=v"(r) : "v"(a), "v"(b));
    return r;
}

// ~1-ulp sigmoid matching numpy's f32 chain.
__device__ __forceinline__ float sigmoid_ref(float t) {
    float e = expf(-t);                      // ocml expf, ~1 ulp f32
    return (float)(1.0 / (1.0 + (double)e)); // exact add+div, one rounding
}

// ---- Phase A1: fused corner-pack of grid1 (barrier-free, PLAIN stores) ----
// pk cell (u,v) = [s(t00).xy s(t01).xy | s(t10).xy s(t11).xy]  (32B)
__global__ void __launch_bounds__(256) pack_fused_kernel(
    const float* __restrict__ g1, float* __restrict__ pk, int U1)
{
    int v = blockIdx.x * 256 + threadIdx.x;
    int u = blockIdx.y;
    if (v >= U1) return;
    int v1 = v + 1; if (v1 >= U1) v1 = 0;
    int u1 = u + 1; if (u1 >= U1) u1 = 0;

    const f32x2* g = reinterpret_cast<const f32x2*>(g1);
    size_t ru0 = (size_t)u  * U1;
    size_t ru1 = (size_t)u1 * U1;
    f32x2 t00 = g[ru0 + v];
    f32x2 t01 = g[ru0 + v1];
    f32x2 t10 = g[ru1 + v];
    f32x2 t11 = g[ru1 + v1];

    f32x4 lo, hi;
    lo.x = sigmoid_ref(t00.x); lo.y = sigmoid_ref(t00.y);
    lo.z = sigmoid_ref(t01.x); lo.w = sigmoid_ref(t01.y);
    hi.x = sigmoid_ref(t10.x); hi.y = sigmoid_ref(t10.y);
    hi.z = sigmoid_ref(t11.x); hi.w = sigmoid_ref(t11.y);

    f32x4* o = reinterpret_cast<f32x4*>(pk + (ru0 + v) * 8);
    o[0] = lo;
    o[1] = hi;
}

// ---- Phase A2: elementwise sigmoid of a table (float4-vectorized) ----
__global__ void __launch_bounds__(256) sigmoid_table_kernel(
    const float4* __restrict__ in, float4* __restrict__ out, int n4)
{
    int i = blockIdx.x * blockDim.x + threadIdx.x;
    if (i >= n4) return;
    float4 v = in[i];
    float4 r;
    r.x = sigmoid_ref(v.x);
    r.y = sigmoid_ref(v.y);
    r.z = sigmoid_ref(v.z);
    r.w = sigmoid_ref(v.w);
    out[i] = r;
}

// ---- Phase B: 1pt/thread packed query, vector stage-2 ----
__global__ void __launch_bounds__(256) query_packed_kernel(
    const float* __restrict__ x,
    const float* __restrict__ pk,   // packed corners, U1*U1*8 floats
    const float* __restrict__ s0,   // sigmoid(grid0), (U0,U0,3), L2-resident
    float* __restrict__ out,        // (N,3)
    int N, int U1, int U0)
{
    int i = blockIdx.x * blockDim.x + threadIdx.x;
    if (i >= N) return;

    f32x2 uv = __builtin_nontemporal_load(
        reinterpret_cast<const f32x2*>(x) + i);

    // stage-1 coords: single rounded f32 mul (contract-proof)
    float fU1 = (float)U1;
    float su = mul_rn_nocontract(uv.x, fU1);
    float sv = mul_rn_nocontract(uv.y, fU1);
    float u0f = floorf(su), v0f = floorf(sv);
    float fu = su - u0f;              // exact
    float fv = sv - v0f;
    int u0 = (int)u0f % U1; if (u0 < 0) u0 += U1;
    int v0 = (int)v0f % U1; if (v0 < 0) v0 += U1;

    // ONE 64B line: 32B-aligned packed cell, plain loads
    const float4* cell = reinterpret_cast<const float4*>(pk)
                       + (size_t)(u0 * U1 + v0) * 2;
    float4 lo = cell[0];   // t00.xy t01.xy
    float4 hi = cell[1];   // t10.xy t11.xy

    float omfu = 1.0f - fu, omfv = 1.0f - fv;
    float kx = (lo.x * omfu + hi.x * fu) * omfv
             + (lo.z * omfu + hi.z * fu) * fv;
    float ky = (lo.y * omfu + hi.y * fu) * omfv
             + (lo.w * omfu + hi.w * fu) * fv;

    // stage-2 coords
    float fU0 = (float)U0;
    float su2 = mul_rn_nocontract(kx, fU0);
    float sv2 = mul_rn_nocontract(ky, fU0);
    float u0f2 = floorf(su2), v0f2 = floorf(sv2);
    float fu2 = su2 - u0f2, fv2 = sv2 - v0f2;
    int p0 = (int)u0f2 % U0; if (p0 < 0) p0 += U0;
    int q0 = (int)v0f2 % U0; if (q0 < 0) q0 += U0;
    int p1 = p0 + 1; if (p1 >= U0) p1 = 0;
    int q1 = q0 + 1; if (q1 >= U0) q1 = 0;

    // stage-2 corner fetch: texels (p,q0),(p,q1) are 6 CONTIGUOUS floats
    // per row when q1==q0+1 (99.8% of pts): one align-4 f32x4 + f32x2
    // per row = 4 loads instead of 12 (transaction model, R21). Same
    // floats, same lines. Wrap (q1==0) lanes take the scalar path.
    float a00, a01, a02, a10, a11, a12;   // row p0: texel q0 | q1
    float b00v, b01v, b02v, b10v, b11v, b12v; // row p1
    if (q1 != 0) {
        const float* r0p = s0 + (size_t)(p0 * U0 + q0) * 3;
        f32x4u h0 = *reinterpret_cast<const f32x4u*>(r0p);
        f32x2u h1 = *reinterpret_cast<const f32x2u*>(r0p + 4);
        a00 = h0.x; a01 = h0.y; a02 = h0.z;
        a10 = h0.w; a11 = h1.x; a12 = h1.y;
        const float* r1p = s0 + (size_t)(p1 * U0 + q0) * 3;
        f32x4u h2 = *reinterpret_cast<const f32x4u*>(r1p);
        f32x2u h3 = *reinterpret_cast<const f32x2u*>(r1p + 4);
        b00v = h2.x; b01v = h2.y; b02v = h2.z;
        b10v = h2.w; b11v = h3.x; b12v = h3.y;
    } else {
        int c00 = (p0 * U0 + q0) * 3, c01 = (p0 * U0 + q1) * 3;
        int c10 = (p1 * U0 + q0) * 3, c11 = (p1 * U0 + q1) * 3;
        a00 = s0[c00+0]; a01 = s0[c00+1]; a02 = s0[c00+2];
        a10 = s0[c01+0]; a11 = s0[c01+1]; a12 = s0[c01+2];
        b00v = s0[c10+0]; b01v = s0[c10+1]; b02v = s0[c10+2];
        b10v = s0[c11+0]; b11v = s0[c11+1]; b12v = s0[c11+2];
    }

    // blends: identical arithmetic/order to the validated scalar form
    //   r_c = (t00*omfu2 + t10*fu2)*omfv2 + (t01*omfu2 + t11*fu2)*fv2
    float omfu2 = 1.0f - fu2, omfv2 = 1.0f - fv2;
    float r0 = (a00 * omfu2 + b00v * fu2) * omfv2
             + (a10 * omfu2 + b10v * fu2) * fv2;
    float r1 = (a01 * omfu2 + b01v * fu2) * omfv2
             + (a11 * omfu2 + b11v * fu2) * fv2;
    float r2 = (a02 * omfu2 + b02v * fu2) * omfv2
             + (a12 * omfu2 + b12v * fu2) * fv2;
    out[3*i+0] = r0; out[3*i+1] = r1; out[3*i+2] = r2;
}

// ---- Middle variant: direct query, no grid1 pre-pass (R17, 197us) ----
__global__ void __launch_bounds__(256) query_direct_kernel(
    const float* __restrict__ x,
    const float* __restrict__ g1,
    const float* __restrict__ s0,
    float* __restrict__ out,
    int N, int U1, int U0)
{
    int i = blockIdx.x * blockDim.x + threadIdx.x;
    if (i >= N) return;

    f32x2 uv = __builtin_nontemporal_load(
        reinterpret_cast<const f32x2*>(x) + i);

    float fU1 = (float)U1;
    float su = mul_rn_nocontract(uv.x, fU1);
    float sv = mul_rn_nocontract(uv.y, fU1);
    float u0f = floorf(su), v0f = floorf(sv);
    float fu = su - u0f, fv = sv - v0f;
    int u0 = (int)u0f % U1; if (u0 < 0) u0 += U1;
    int v0 = (int)v0f % U1; if (v0 < 0) v0 += U1;
    int u1 = u0 + 1; if (u1 >= U1) u1 = 0;
    int v1 = v0 + 1; if (v1 >= U1) v1 = 0;

    const f32x2* g = reinterpret_cast<const f32x2*>(g1);
    const f32x2* row0 = g + (size_t)u0 * U1;
    const f32x2* row1 = g + (size_t)u1 * U1;
    f32x2 t00 = row0[v0];
    f32x2 t01 = row0[v1];
    f32x2 t10 = row1[v0];
    f32x2 t11 = row1[v1];

    float a00x = sigmoid_ref(t00.x), a00y = sigmoid_ref(t00.y);
    float a10x = sigmoid_ref(t10.x), a10y = sigmoid_ref(t10.y);
    float a01x = sigmoid_ref(t01.x), a01y = sigmoid_ref(t01.y);
    float a11x = sigmoid_ref(t11.x), a11y = sigmoid_ref(t11.y);

    float omfu = 1.0f - fu, omfv = 1.0f - fv;
    float kx = (a00x * omfu + a10x * fu) * omfv
             + (a01x * omfu + a11x * fu) * fv;
    float ky = (a00y * omfu + a10y * fu) * omfv
             + (a01y * omfu + a11y * fu) * fv;

    float fU0 = (float)U0;
    float su2 = mul_rn_nocontract(kx, fU0);
    float sv2 = mul_rn_nocontract(ky, fU0);
    float u0f2 = floorf(su2), v0f2 = floorf(sv2);
    float fu2 = su2 - u0f2, fv2 = sv2 - v0f2;
    int p0 = (int)u0f2 % U0; if (p0 < 0) p0 += U0;
    int q0 = (int)v0f2 % U0; if (q0 < 0) q0 += U0;
    int p1 = p0 + 1; if (p1 >= U0) p1 = 0;
    int q1 = q0 + 1; if (q1 >= U0) q1 = 0;
    int b00 = (p0 * U0 + q0) * 3, b10 = (p1 * U0 + q0) * 3;
    int b01 = (p0 * U0 + q1) * 3, b11 = (p1 * U0 + q1) * 3;
    float omfu2 = 1.0f - fu2, omfv2 = 1.0f - fv2;
    float r0 = (s0[b00+0] * omfu2 + s0[b10+0] * fu2) * omfv2
             + (s0[b01+0] * omfu2 + s0[b11+0] * fu2) * fv2;
    float r1 = (s0[b00+1] * omfu2 + s0[b10+1] * fu2) * omfv2
             + (s0[b01+1] * omfu2 + s0[b11+1] * fu2) * fv2;
    float r2 = (s0[b00+2] * omfu2 + s0[b10+2] * fu2) * omfv2
             + (s0[b01+2] * omfu2 + s0[b11+2] * fu2) * fv2;
    out[3*i+0] = r0; out[3*i+1] = r1; out[3*i+2] = r2;
}

// ---- Full fallback: all sigmoids in-kernel (ws too small) ----
__global__ void __launch_bounds__(256) query_kernel_fallback(
    const float* __restrict__ x,
    const float* __restrict__ g1,
    const float* __restrict__ g0,
    float* __restrict__ out,
    int N, int U1, int U0)
{
    int i = blockIdx.x * blockDim.x + threadIdx.x;
    if (i >= N) return;
    float2 uv = reinterpret_cast<const float2*>(x)[i];
    float fU1 = (float)U1;
    float su = mul_rn_nocontract(uv.x, fU1);
    float sv = mul_rn_nocontract(uv.y, fU1);
    float u0f = floorf(su), v0f = floorf(sv);
    float fu = su - u0f, fv = sv - v0f;
    int u0 = (int)u0f % U1; if (u0 < 0) u0 += U1;
    int v0 = (int)v0f % U1; if (v0 < 0) v0 += U1;
    int u1 = u0 + 1; if (u1 >= U1) u1 = 0;
    int v1 = v0 + 1; if (v1 >= U1) v1 = 0;
    const float2* g1v = reinterpret_cast<const float2*>(g1);
    float2 t00 = g1v[u0 * U1 + v0];
    float2 t10 = g1v[u1 * U1 + v0];
    float2 t01 = g1v[u0 * U1 + v1];
    float2 t11 = g1v[u1 * U1 + v1];
    float a00x = sigmoid_ref(t00.x), a00y = sigmoid_ref(t00.y);
    float a10x = sigmoid_ref(t10.x), a10y = sigmoid_ref(t10.y);
    float a01x = sigmoid_ref(t01.x), a01y = sigmoid_ref(t01.y);
    float a11x = sigmoid_ref(t11.x), a11y = sigmoid_ref(t11.y);
    float omfu = 1.0f - fu, omfv = 1.0f - fv;
    float kx = (a00x * omfu + a10x * fu) * omfv + (a01x * omfu + a11x * fu) * fv;
    float ky = (a00y * omfu + a10y * fu) * omfv + (a01y * omfu + a11y * fu) * fv;
    float fU0 = (float)U0;
    float su2 = mul_rn_nocontract(kx, fU0);
    float sv2 = mul_rn_nocontract(ky, fU0);
    float u0f2 = floorf(su2), v0f2 = floorf(sv2);
    float fu2 = su2 - u0f2, fv2 = sv2 - v0f2;
    int p0 = (int)u0f2 % U0; if (p0 < 0) p0 += U0;
    int q0 = (int)v0f2 % U0; if (q0 < 0) q0 += U0;
    int p1 = p0 + 1; if (p1 >= U0) p1 = 0;
    int q1 = q0 + 1; if (q1 >= U0) q1 = 0;
    int b00 = (p0 * U0 + q0) * 3, b10 = (p1 * U0 + q0) * 3;
    int b01 = (p0 * U0 + q1) * 3, b11 = (p1 * U0 + q1) * 3;
    float omfu2 = 1.0f - fu2, omfv2 = 1.0f - fv2;
    float r0 = (sigmoid_ref(g0[b00+0]) * omfu2 + sigmoid_ref(g0[b10+0]) * fu2) * omfv2
             + (sigmoid_ref(g0[b01+0]) * omfu2 + sigmoid_ref(g0[b11+0]) * fu2) * fv2;
    float r1 = (sigmoid_ref(g0[b00+1]) * omfu2 + sigmoid_ref(g0[b10+1]) * fu2) * omfv2
             + (sigmoid_ref(g0[b01+1]) * omfu2 + sigmoid_ref(g0[b11+1]) * fu2) * fv2;
    float r2 = (sigmoid_ref(g0[b00+2]) * omfu2 + sigmoid_ref(g0[b10+2]) * fu2) * omfv2
             + (sigmoid_ref(g0[b01+2]) * omfu2 + sigmoid_ref(g0[b11+2]) * fu2) * fv2;
    out[3*i+0] = r0; out[3*i+1] = r1; out[3*i+2] = r2;
}

extern "C" void kernel_launch(void* const* d_in, const int* in_sizes, int n_in,
                              void* d_out, int out_size, void* d_ws, size_t ws_size,
                              hipStream_t stream) {
    const float* x  = (const float*)d_in[0];
    const float* g1 = (const float*)d_in[1];
    const float* g0 = (const float*)d_in[2];
    float* out = (float*)d_out;

    int N = in_sizes[0] / 2;
    long long n1 = in_sizes[1];          // U1*U1*2
    long long n0 = in_sizes[2];          // U0*U0*3
    int U1 = (int)(sqrt((double)(n1 / 2)) + 0.5);
    int U0 = (int)(sqrt((double)(n0 / 3)) + 0.5);
    long long ncells1 = (long long)U1 * U1;

    int block = 256;
    size_t need_packed = ((size_t)ncells1 * 8 + (size_t)n0) * sizeof(float);
    size_t need_s0     = (size_t)n0 * sizeof(float);

    if (ws_size >= need_packed && (n0 % 4) == 0) {
        float* pk = (float*)d_ws;                     // 138.4 MB packed
        float* s0 = pk + ncells1 * 8;                 // 3.2 MB sigmoided g0
        int n0_4 = (int)(n0 / 4);
        dim3 pgrid((U1 + block - 1) / block, U1);
        pack_fused_kernel<<<pgrid, block, 0, stream>>>(g1, pk, U1);
        sigmoid_table_kernel<<<(n0_4 + block - 1) / block, block, 0, stream>>>(
            (const float4*)g0, (float4*)s0, n0_4);
        query_packed_kernel<<<(N + block - 1) / block, block, 0, stream>>>(
            x, pk, s0, out, N, U1, U0);
    } else if (ws_size >= need_s0 && (n0 % 4) == 0) {
        float* s0 = (float*)d_ws;                     // 3.2 MB sigmoided g0
        int n0_4 = (int)(n0 / 4);
        sigmoid_table_kernel<<<(n0_4 + block - 1) / block, block, 0, stream>>>(
            (const float4*)g0, (float4*)s0, n0_4);
        query_direct_kernel<<<(N + block - 1) / block, block, 0, stream>>>(
            x, g1, s0, out, N, U1, U0);
    } else {
        query_kernel_fallback<<<(N + block - 1) / block, block, 0, stream>>>(
            x, g1, g0, out, N, U1, U0);
    }
}

// Round 11
// 237.303 us; speedup vs baseline: 1.2218x; 1.0529x over previous
//
#include <hip/hip_runtime.h>
#include <math.h>

// Chained bilinear lookup: out = bilinear(grid0, bilinear(grid1, x)),
// sigmoid per corner sample (both stages).
//
// Shapes: x (N,2) f32; grid1 (U1,U1,2) f32, U1=2080; grid0 (U0,U0,3) f32,
// U0=520; out (N,3) f32.
//
// PRECISION CONTRACT (R0-R21, passing at absmax 3.9e-3 / thr 1.96e-2):
//  - su = x*U must be a SINGLE f32 rounded mul (inline-asm v_mul_f32).
//  - Sigmoid: e = expf(-t) f32, then 1/(1+e) in f64 rounded once.
//    In-query stage-1 sigmoids are value-identical (same fn/order).
//  - f32 blends as written. Vector-loading the same s0 floats is
//    value-identical.
//
// COST MODEL: dur_us = kernels + ~88us FIXED harness overhead.
// LEDGER @R21 (best 249.9): query_packed 113.3 + pack_fused 44.6 +
// sig 4 + 88. Query is near the 3.54TB/s random-line service ceiling
// on its 312MB min-fetch (one 64B line/pt): ~10us headroom. Pack moves
// 173MB @ 3.9TB/s (write-stream limited).
// MECHANISMS (measured):
//  - nt STORES on a ws table cost the query ~18us (L3 residency lost;
//    R18 pk A/B 142 vs 124). PLAIN stores for all ws tables.
//  - nt LOADS in query: -41% (R14). NEVER.
//  - vector stage-2 (12->4 s0 loads): -11us (R21).
//  - MLP per thread: null (R19/R20). Write coalescing: 12B/pt
//    wave-contiguous only (R19: 24B/thread cost +13us).
//
// R22 (this): switch to ROWPAIR format to halve pack bytes:
//   rp[u][v] = {g1[u][v].xy, g1[u+1][v].xy} (16B, raw, PLAIN stores)
//   pack: 104MB moved -> predict 26-30us (vs fused 44.6).
//   query: R16 rowpair (2 adjacent entries = 80B/pt, 8 in-kernel
//   sigmoids) + R21 vector stage-2 + L3-resident rp. Predict 112-122us
//   (R16's 141 had nt-rp ~+18 and scalar stage-2 ~+11).
//   Total predict 230-244. If query >130: revert to R21 config.

typedef float f32x2 __attribute__((ext_vector_type(2)));
typedef float f32x4 __attribute__((ext_vector_type(4)));
typedef float f32x4u __attribute__((ext_vector_type(4), aligned(4)));
typedef float f32x2u __attribute__((ext_vector_type(2), aligned(4)));

__device__ __forceinline__ float mul_rn_nocontract(float a, float b) {
    float r;
    asm("v_mul_f32 %0, %1, %2" : "=v"(r) : "v"(a), "v"(b));
    return r;
}

// ~1-ulp sigmoid matching numpy's f32 chain.
__device__ __forceinline__ float sigmoid_ref(float t) {
    float e = expf(-t);                      // ocml expf, ~1 ulp f32
    return (float)(1.0 / (1.0 + (double)e)); // exact add+div, one rounding
}

// ---- Phase A1: raw row-pair repack of grid1 (PLAIN stores) ----
// rp[u][v] = {g1[u][v].x, .y, g1[u+1 mod U1][v].x, .y}  (16B)
// Plain stores keep rp (69MB) L3-resident for the query (R18 lesson).
__global__ void __launch_bounds__(256) rowpair_pack_kernel(
    const float* __restrict__ g1, float* __restrict__ rp, int U1)
{
    int v = blockIdx.x * 256 + threadIdx.x;
    int u = blockIdx.y;
    if (v >= U1) return;
    int u1 = u + 1; if (u1 >= U1) u1 = 0;

    const f32x2* g = reinterpret_cast<const f32x2*>(g1);
    f32x2 a = g[(size_t)u  * U1 + v];
    f32x2 b = g[(size_t)u1 * U1 + v];
    f32x4 e;
    e.x = a.x; e.y = a.y; e.z = b.x; e.w = b.y;
    reinterpret_cast<f32x4*>(rp)[(size_t)u * U1 + v] = e;
}

// ---- Phase A2: elementwise sigmoid of a table (float4-vectorized) ----
__global__ void __launch_bounds__(256) sigmoid_table_kernel(
    const float4* __restrict__ in, float4* __restrict__ out, int n4)
{
    int i = blockIdx.x * blockDim.x + threadIdx.x;
    if (i >= n4) return;
    float4 v = in[i];
    float4 r;
    r.x = sigmoid_ref(v.x);
    r.y = sigmoid_ref(v.y);
    r.z = sigmoid_ref(v.z);
    r.w = sigmoid_ref(v.w);
    out[i] = r;
}

// ---- Phase B: rowpair query, in-kernel stage-1 sigmoids, vector stage-2 ----
__global__ void __launch_bounds__(256) query_rowpair_kernel(
    const float* __restrict__ x,
    const float* __restrict__ rp,   // row-pair raw corners, U1*U1*4 floats
    const float* __restrict__ s0,   // sigmoid(grid0), (U0,U0,3)
    float* __restrict__ out,        // (N,3)
    int N, int U1, int U0)
{
    int i = blockIdx.x * blockDim.x + threadIdx.x;
    if (i >= N) return;

    f32x2 uv = __builtin_nontemporal_load(
        reinterpret_cast<const f32x2*>(x) + i);

    // stage-1 coords: single rounded f32 mul (contract-proof)
    float fU1 = (float)U1;
    float su = mul_rn_nocontract(uv.x, fU1);
    float sv = mul_rn_nocontract(uv.y, fU1);
    float u0f = floorf(su), v0f = floorf(sv);
    float fu = su - u0f;              // exact
    float fv = sv - v0f;
    int u0 = (int)u0f % U1; if (u0 < 0) u0 += U1;
    int v0 = (int)v0f % U1; if (v0 < 0) v0 += U1;
    int v1 = v0 + 1; if (v1 >= U1) v1 = 0;

    // two adjacent 16B entries (32B span, 1 line 75% / 2 lines 25%);
    // PLAIN loads (R14); rp is L3-resident (plain-stored, R18)
    const f32x4* rpv = reinterpret_cast<const f32x4*>(rp)
                     + (size_t)u0 * U1;
    f32x4 e0 = rpv[v0];   // t00.xy | t10.xy
    f32x4 e1 = rpv[v1];   // t01.xy | t11.xy

    // stage-1 sigmoids in-kernel (identical fn/order as packed path)
    float a00x = sigmoid_ref(e0.x), a00y = sigmoid_ref(e0.y);
    float a10x = sigmoid_ref(e0.z), a10y = sigmoid_ref(e0.w);
    float a01x = sigmoid_ref(e1.x), a01y = sigmoid_ref(e1.y);
    float a11x = sigmoid_ref(e1.z), a11y = sigmoid_ref(e1.w);

    float omfu = 1.0f - fu, omfv = 1.0f - fv;
    float kx = (a00x * omfu + a10x * fu) * omfv
             + (a01x * omfu + a11x * fu) * fv;
    float ky = (a00y * omfu + a10y * fu) * omfv
             + (a01y * omfu + a11y * fu) * fv;

    // stage-2 coords
    float fU0 = (float)U0;
    float su2 = mul_rn_nocontract(kx, fU0);
    float sv2 = mul_rn_nocontract(ky, fU0);
    float u0f2 = floorf(su2), v0f2 = floorf(sv2);
    float fu2 = su2 - u0f2, fv2 = sv2 - v0f2;
    int p0 = (int)u0f2 % U0; if (p0 < 0) p0 += U0;
    int q0 = (int)v0f2 % U0; if (q0 < 0) q0 += U0;
    int p1 = p0 + 1; if (p1 >= U0) p1 = 0;
    int q1 = q0 + 1; if (q1 >= U0) q1 = 0;

    // stage-2 corner fetch: 6 contiguous floats per row when q1==q0+1
    // (99.8%): align-4 f32x4 + f32x2 per row = 4 loads not 12 (R21,
    // -11us). Same floats, same lines, same blend order. Wrap lanes
    // (q1==0) take the scalar path.
    float a00, a01, a02, a10, a11, a12;       // row p0: texel q0 | q1
    float b00v, b01v, b02v, b10v, b11v, b12v; // row p1
    if (q1 != 0) {
        const float* r0p = s0 + (size_t)(p0 * U0 + q0) * 3;
        f32x4u h0 = *reinterpret_cast<const f32x4u*>(r0p);
        f32x2u h1 = *reinterpret_cast<const f32x2u*>(r0p + 4);
        a00 = h0.x; a01 = h0.y; a02 = h0.z;
        a10 = h0.w; a11 = h1.x; a12 = h1.y;
        const float* r1p = s0 + (size_t)(p1 * U0 + q0) * 3;
        f32x4u h2 = *reinterpret_cast<const f32x4u*>(r1p);
        f32x2u h3 = *reinterpret_cast<const f32x2u*>(r1p + 4);
        b00v = h2.x; b01v = h2.y; b02v = h2.z;
        b10v = h2.w; b11v = h3.x; b12v = h3.y;
    } else {
        int c00 = (p0 * U0 + q0) * 3, c01 = (p0 * U0 + q1) * 3;
        int c10 = (p1 * U0 + q0) * 3, c11 = (p1 * U0 + q1) * 3;
        a00 = s0[c00+0]; a01 = s0[c00+1]; a02 = s0[c00+2];
        a10 = s0[c01+0]; a11 = s0[c01+1]; a12 = s0[c01+2];
        b00v = s0[c10+0]; b01v = s0[c10+1]; b02v = s0[c10+2];
        b10v = s0[c11+0]; b11v = s0[c11+1]; b12v = s0[c11+2];
    }

    float omfu2 = 1.0f - fu2, omfv2 = 1.0f - fv2;
    float r0 = (a00 * omfu2 + b00v * fu2) * omfv2
             + (a10 * omfu2 + b10v * fu2) * fv2;
    float r1 = (a01 * omfu2 + b01v * fu2) * omfv2
             + (a11 * omfu2 + b11v * fu2) * fv2;
    float r2 = (a02 * omfu2 + b02v * fu2) * omfv2
             + (a12 * omfu2 + b12v * fu2) * fv2;
    out[3*i+0] = r0; out[3*i+1] = r1; out[3*i+2] = r2;
}

// ---- Middle variant: direct query, no grid1 pre-pass (R17, 197us) ----
__global__ void __launch_bounds__(256) query_direct_kernel(
    const float* __restrict__ x,
    const float* __restrict__ g1,
    const float* __restrict__ s0,
    float* __restrict__ out,
    int N, int U1, int U0)
{
    int i = blockIdx.x * blockDim.x + threadIdx.x;
    if (i >= N) return;

    f32x2 uv = __builtin_nontemporal_load(
        reinterpret_cast<const f32x2*>(x) + i);

    float fU1 = (float)U1;
    float su = mul_rn_nocontract(uv.x, fU1);
    float sv = mul_rn_nocontract(uv.y, fU1);
    float u0f = floorf(su), v0f = floorf(sv);
    float fu = su - u0f, fv = sv - v0f;
    int u0 = (int)u0f % U1; if (u0 < 0) u0 += U1;
    int v0 = (int)v0f % U1; if (v0 < 0) v0 += U1;
    int u1 = u0 + 1; if (u1 >= U1) u1 = 0;
    int v1 = v0 + 1; if (v1 >= U1) v1 = 0;

    const f32x2* g = reinterpret_cast<const f32x2*>(g1);
    const f32x2* row0 = g + (size_t)u0 * U1;
    const f32x2* row1 = g + (size_t)u1 * U1;
    f32x2 t00 = row0[v0];
    f32x2 t01 = row0[v1];
    f32x2 t10 = row1[v0];
    f32x2 t11 = row1[v1];

    float a00x = sigmoid_ref(t00.x), a00y = sigmoid_ref(t00.y);
    float a10x = sigmoid_ref(t10.x), a10y = sigmoid_ref(t10.y);
    float a01x = sigmoid_ref(t01.x), a01y = sigmoid_ref(t01.y);
    float a11x = sigmoid_ref(t11.x), a11y = sigmoid_ref(t11.y);

    float omfu = 1.0f - fu, omfv = 1.0f - fv;
    float kx = (a00x * omfu + a10x * fu) * omfv
             + (a01x * omfu + a11x * fu) * fv;
    float ky = (a00y * omfu + a10y * fu) * omfv
             + (a01y * omfu + a11y * fu) * fv;

    float fU0 = (float)U0;
    float su2 = mul_rn_nocontract(kx, fU0);
    float sv2 = mul_rn_nocontract(ky, fU0);
    float u0f2 = floorf(su2), v0f2 = floorf(sv2);
    float fu2 = su2 - u0f2, fv2 = sv2 - v0f2;
    int p0 = (int)u0f2 % U0; if (p0 < 0) p0 += U0;
    int q0 = (int)v0f2 % U0; if (q0 < 0) q0 += U0;
    int p1 = p0 + 1; if (p1 >= U0) p1 = 0;
    int q1 = q0 + 1; if (q1 >= U0) q1 = 0;
    int b00 = (p0 * U0 + q0) * 3, b10 = (p1 * U0 + q0) * 3;
    int b01 = (p0 * U0 + q1) * 3, b11 = (p1 * U0 + q1) * 3;
    float omfu2 = 1.0f - fu2, omfv2 = 1.0f - fv2;
    float r0 = (s0[b00+0] * omfu2 + s0[b10+0] * fu2) * omfv2
             + (s0[b01+0] * omfu2 + s0[b11+0] * fu2) * fv2;
    float r1 = (s0[b00+1] * omfu2 + s0[b10+1] * fu2) * omfv2
             + (s0[b01+1] * omfu2 + s0[b11+1] * fu2) * fv2;
    float r2 = (s0[b00+2] * omfu2 + s0[b10+2] * fu2) * omfv2
             + (s0[b01+2] * omfu2 + s0[b11+2] * fu2) * fv2;
    out[3*i+0] = r0; out[3*i+1] = r1; out[3*i+2] = r2;
}

// ---- Full fallback: all sigmoids in-kernel (ws too small) ----
__global__ void __launch_bounds__(256) query_kernel_fallback(
    const float* __restrict__ x,
    const float* __restrict__ g1,
    const float* __restrict__ g0,
    float* __restrict__ out,
    int N, int U1, int U0)
{
    int i = blockIdx.x * blockDim.x + threadIdx.x;
    if (i >= N) return;
    float2 uv = reinterpret_cast<const float2*>(x)[i];
    float fU1 = (float)U1;
    float su = mul_rn_nocontract(uv.x, fU1);
    float sv = mul_rn_nocontract(uv.y, fU1);
    float u0f = floorf(su), v0f = floorf(sv);
    float fu = su - u0f, fv = sv - v0f;
    int u0 = (int)u0f % U1; if (u0 < 0) u0 += U1;
    int v0 = (int)v0f % U1; if (v0 < 0) v0 += U1;
    int u1 = u0 + 1; if (u1 >= U1) u1 = 0;
    int v1 = v0 + 1; if (v1 >= U1) v1 = 0;
    const float2* g1v = reinterpret_cast<const float2*>(g1);
    float2 t00 = g1v[u0 * U1 + v0];
    float2 t10 = g1v[u1 * U1 + v0];
    float2 t01 = g1v[u0 * U1 + v1];
    float2 t11 = g1v[u1 * U1 + v1];
    float a00x = sigmoid_ref(t00.x), a00y = sigmoid_ref(t00.y);
    float a10x = sigmoid_ref(t10.x), a10y = sigmoid_ref(t10.y);
    float a01x = sigmoid_ref(t01.x), a01y = sigmoid_ref(t01.y);
    float a11x = sigmoid_ref(t11.x), a11y = sigmoid_ref(t11.y);
    float omfu = 1.0f - fu, omfv = 1.0f - fv;
    float kx = (a00x * omfu + a10x * fu) * omfv + (a01x * omfu + a11x * fu) * fv;
    float ky = (a00y * omfu + a10y * fu) * omfv + (a01y * omfu + a11y * fu) * fv;
    float fU0 = (float)U0;
    float su2 = mul_rn_nocontract(kx, fU0);
    float sv2 = mul_rn_nocontract(ky, fU0);
    float u0f2 = floorf(su2), v0f2 = floorf(sv2);
    float fu2 = su2 - u0f2, fv2 = sv2 - v0f2;
    int p0 = (int)u0f2 % U0; if (p0 < 0) p0 += U0;
    int q0 = (int)v0f2 % U0; if (q0 < 0) q0 += U0;
    int p1 = p0 + 1; if (p1 >= U0) p1 = 0;
    int q1 = q0 + 1; if (q1 >= U0) q1 = 0;
    int b00 = (p0 * U0 + q0) * 3, b10 = (p1 * U0 + q0) * 3;
    int b01 = (p0 * U0 + q1) * 3, b11 = (p1 * U0 + q1) * 3;
    float omfu2 = 1.0f - fu2, omfv2 = 1.0f - fv2;
    float r0 = (sigmoid_ref(g0[b00+0]) * omfu2 + sigmoid_ref(g0[b10+0]) * fu2) * omfv2
             + (sigmoid_ref(g0[b01+0]) * omfu2 + sigmoid_ref(g0[b11+0]) * fu2) * fv2;
    float r1 = (sigmoid_ref(g0[b00+1]) * omfu2 + sigmoid_ref(g0[b10+1]) * fu2) * omfv2
             + (sigmoid_ref(g0[b01+1]) * omfu2 + sigmoid_ref(g0[b11+1]) * fu2) * fv2;
    float r2 = (sigmoid_ref(g0[b00+2]) * omfu2 + sigmoid_ref(g0[b10+2]) * fu2) * omfv2
             + (sigmoid_ref(g0[b01+2]) * omfu2 + sigmoid_ref(g0[b11+2]) * fu2) * fv2;
    out[3*i+0] = r0; out[3*i+1] = r1; out[3*i+2] = r2;
}

extern "C" void kernel_launch(void* const* d_in, const int* in_sizes, int n_in,
                              void* d_out, int out_size, void* d_ws, size_t ws_size,
                              hipStream_t stream) {
    const float* x  = (const float*)d_in[0];
    const float* g1 = (const float*)d_in[1];
    const float* g0 = (const float*)d_in[2];
    float* out = (float*)d_out;

    int N = in_sizes[0] / 2;
    long long n1 = in_sizes[1];          // U1*U1*2
    long long n0 = in_sizes[2];          // U0*U0*3
    int U1 = (int)(sqrt((double)(n1 / 2)) + 0.5);
    int U0 = (int)(sqrt((double)(n0 / 3)) + 0.5);
    long long ncells1 = (long long)U1 * U1;

    int block = 256;
    size_t need_rowpair = ((size_t)ncells1 * 4 + (size_t)n0) * sizeof(float);
    size_t need_s0      = (size_t)n0 * sizeof(float);

    if (ws_size >= need_rowpair && (n0 % 4) == 0) {
        float* rp = (float*)d_ws;                     // 69.2 MB row-pair raw
        float* s0 = rp + ncells1 * 4;                 // 3.2 MB sigmoided g0
        int n0_4 = (int)(n0 / 4);
        dim3 pgrid((U1 + block - 1) / block, U1);
        rowpair_pack_kernel<<<pgrid, block, 0, stream>>>(g1, rp, U1);
        sigmoid_table_kernel<<<(n0_4 + block - 1) / block, block, 0, stream>>>(
            (const float4*)g0, (float4*)s0, n0_4);
        query_rowpair_kernel<<<(N + block - 1) / block, block, 0, stream>>>(
            x, rp, s0, out, N, U1, U0);
    } else if (ws_size >= need_s0 && (n0 % 4) == 0) {
        float* s0 = (float*)d_ws;                     // 3.2 MB sigmoided g0
        int n0_4 = (int)(n0 / 4);
        sigmoid_table_kernel<<<(n0_4 + block - 1) / block, block, 0, stream>>>(
            (const float4*)g0, (float4*)s0, n0_4);
        query_direct_kernel<<<(N + block - 1) / block, block, 0, stream>>>(
            x, g1, s0, out, N, U1, U0);
    } else {
        query_kernel_fallback<<<(N + block - 1) / block, block, 0, stream>>>(
            x, g1, g0, out, N, U1, U0);
    }
}